// Round 5
// baseline (255.596 us; speedup 1.0000x reference)
//
#include <hip/hip_runtime.h>

// Convoluzione: VALID 3x3 cross-correlation, NCHW.
// img [32,128,56,56] f32, filtro [256,128,3,3] f32 -> out [32,256,54,54] f32
// bf16 MFMA implicit shift-conv, filters split hi/lo bf16.
// R5: filters global->reg (no LDS), img double-buffered DMA, 4 barriers total,
//     setprio around MFMA bursts.

#define BB   32
#define CIN  128
#define COUT 256
#define HH   56
#define WW   56
#define OH   54
#define OW   54

typedef short bf16x8 __attribute__((ext_vector_type(8)));
typedef float f32x4  __attribute__((ext_vector_type(4)));
typedef unsigned short u16x8 __attribute__((ext_vector_type(8)));

#define GLOAD_LDS16(g, l) __builtin_amdgcn_global_load_lds( \
    (const __attribute__((address_space(1))) unsigned int*)(g), \
    (__attribute__((address_space(3))) unsigned int*)(l), 16, 0, 0)

static __device__ __forceinline__ unsigned short f2bf(float f) {
    unsigned int u = __float_as_uint(f);
    u += 0x7FFFu + ((u >> 16) & 1u);
    return (unsigned short)(u >> 16);
}
static __device__ __forceinline__ float bf2f(unsigned short h) {
    return __uint_as_float(((unsigned int)h) << 16);
}

// ---------------- prep 1: img f32 NCHW -> imgT bf16 [b][y][x][ci] ----------
__global__ __launch_bounds__(256) void prep_img(const float* __restrict__ img,
                                                unsigned short* __restrict__ imgT) {
    const int b = blockIdx.x / HH;
    const int y = blockIdx.x - b * HH;
    for (int i = threadIdx.x; i < 16 * WW; i += 256) {
        const int g = i / WW;
        const int x = i - g * WW;
        unsigned short pk[8];
        #pragma unroll
        for (int j = 0; j < 8; ++j)
            pk[j] = f2bf(img[((size_t)(b * CIN + g * 8 + j) * HH + y) * WW + x]);
        *(u16x8*)(imgT + ((size_t)(b * HH + y) * WW + x) * CIN + g * 8) = *(u16x8*)pk;
    }
}

// ---------------- prep 2: filtro f32 OIHW -> filtT bf16 [t*2+p][co][ci] -----
__global__ __launch_bounds__(256) void prep_flt(const float* __restrict__ flt,
                                                unsigned short* __restrict__ filtT) {
    const int idx = blockIdx.x * 256 + threadIdx.x;
    const int co = idx >> 7;
    const int ci = idx & 127;
    float v[9];
    #pragma unroll
    for (int t = 0; t < 9; ++t) v[t] = flt[(size_t)(co * CIN + ci) * 9 + t];
    #pragma unroll
    for (int t = 0; t < 9; ++t) {
        unsigned short h = f2bf(v[t]);
        unsigned short l = f2bf(v[t] - bf2f(h));
        filtT[((size_t)(t * 2 + 0) * COUT + co) * CIN + ci] = h;
        filtT[((size_t)(t * 2 + 1) * COUT + co) * CIN + ci] = l;
    }
}

// ---------------- conv kernel ----------------------------------------------
// Block: 256 thr / 4 waves. Tile: 64 co x 8 rows x 56 cols; wave wv = row pair.
// A (filters) global->reg, 1-tap-ahead pipeline. B (img) from LDS, double buf.
// LDS img buffer: 4 ci-oct planes x 576 sites x 16B (9216 B/plane, 16-site pad
// absorbs the x<=57 read overflow). Two buffers, 73728 B total.
#define IMG_ROWB  896            // 56 sites * 16 B
#define IMG_PLANE 9216           // 576 sites * 16 B (560 used + pad)
#define IMG_BUF   36864          // 4 planes
#define LDS_BYTES 73728          // 2 buffers

__global__ __launch_bounds__(256, 2) void conv_mfma(
    const unsigned short* __restrict__ imgT,
    const unsigned short* __restrict__ filtT,
    float* __restrict__ out)
{
    __shared__ char lds[LDS_BYTES];

    const int tid  = threadIdx.x;
    const int lane = tid & 63, wv = tid >> 6;
    const int sub  = lane & 15, kg = lane >> 4;
    const int ysub = sub >> 3,  xl = sub & 7;

    // XCD swizzle (896 = 8*112), cot fastest -> 4 blocks share img tile in L2
    const int w    = (blockIdx.x & 7) * 112 + (blockIdx.x >> 3);
    const int cot  = w & 3;
    const int rest = w >> 2;
    const int strip = rest % 7;
    const int b     = rest / 7;
    const int co0   = cot * 64;
    const int ystart = (strip < 6) ? strip * 8 : (OH - 8);

    char* const pImg = lds;
    const char* bB = pImg + kg * IMG_PLANE + (2 * wv + ysub) * IMG_ROWB + xl * 16;
    // A-fragment per-lane base (elements): (tp, co0+sub+m*16, kg*8 + c*32)
    const unsigned short* fbase = filtT + (co0 + sub) * CIN + kg * 8;

    // staging: wave wv stages plane wv; 9 rounds x 64 lanes = 576 sites
    // (sites 560..575 are pad; their global reads land a few KB past imgT,
    //  still inside d_ws (filtT follows) — values never consumed)
    int goff[9];
    #pragma unroll
    for (int r_ = 0; r_ < 9; ++r_) {
        const int site = r_ * 64 + lane;
        const int rr = site / 56;
        const int xx = site - rr * 56;
        goff[r_] = ((b * HH + ystart + rr) * WW + xx) * CIN + wv * 8;
    }

    f32x4 acc[4][7];
    #pragma unroll
    for (int m = 0; m < 4; ++m)
        #pragma unroll
        for (int nf = 0; nf < 7; ++nf) acc[m][nf] = (f32x4)0.0f;

    #define STAGE(cn) do {                                                   \
        char* dst_ = pImg + ((cn) & 1) * IMG_BUF + wv * IMG_PLANE;           \
        _Pragma("unroll")                                                    \
        for (int r_ = 0; r_ < 9; ++r_)                                       \
            GLOAD_LDS16(imgT + goff[r_] + (cn) * 32,                         \
                        dst_ + r_ * 1024 + lane * 16);                       \
    } while (0)

    bf16x8 Ab[2][8];
    #pragma unroll
    for (int m = 0; m < 4; ++m) {                      // preload (c=0, t=0)
        Ab[0][m * 2 + 0] = *(const bf16x8*)(fbase + 0 * 32768 + m * 2048);
        Ab[0][m * 2 + 1] = *(const bf16x8*)(fbase + 1 * 32768 + m * 2048);
    }

    STAGE(0);
    __syncthreads();

    #pragma unroll
    for (int c = 0; c < 4; ++c) {
        if (c > 0) __syncthreads();
        if (c < 3) STAGE(c + 1);
        const char* bBc = bB + (c & 1) * IMG_BUF;
        #pragma unroll
        for (int t = 0; t < 9; ++t) {
            const int par = (c * 9 + t) & 1;           // compile-time after unroll
            const int nxp = par ^ 1;
            if (t < 8) {                               // prefetch next tap's A
                #pragma unroll
                for (int m = 0; m < 4; ++m) {
                    Ab[nxp][m*2+0] = *(const bf16x8*)(fbase + (2*(t+1)+0)*32768 + m*2048 + c*32);
                    Ab[nxp][m*2+1] = *(const bf16x8*)(fbase + (2*(t+1)+1)*32768 + m*2048 + c*32);
                }
            } else if (c < 3) {                        // prefetch next c's tap 0
                #pragma unroll
                for (int m = 0; m < 4; ++m) {
                    Ab[nxp][m*2+0] = *(const bf16x8*)(fbase + 0*32768 + m*2048 + (c+1)*32);
                    Ab[nxp][m*2+1] = *(const bf16x8*)(fbase + 1*32768 + m*2048 + (c+1)*32);
                }
            }
            const int dy = t / 3, dx = t % 3;
            __builtin_amdgcn_s_setprio(1);
            #pragma unroll
            for (int nf = 0; nf < 7; ++nf) {
                bf16x8 bv = *(const bf16x8*)(bBc + dy * IMG_ROWB + (nf * 8 + dx) * 16);
                #pragma unroll
                for (int m = 0; m < 4; ++m) {
                    acc[m][nf] = __builtin_amdgcn_mfma_f32_16x16x32_bf16(Ab[par][m*2+0], bv, acc[m][nf], 0, 0, 0);
                    acc[m][nf] = __builtin_amdgcn_mfma_f32_16x16x32_bf16(Ab[par][m*2+1], bv, acc[m][nf], 0, 0, 0);
                }
            }
            __builtin_amdgcn_s_setprio(0);
        }
    }
    #undef STAGE

    // epilogue: D col=lane&15 -> spatial, row=kg*4+j -> co
    const int y = ystart + 2 * wv + ysub;
    #pragma unroll
    for (int m = 0; m < 4; ++m) {
        const int cob = co0 + m * 16 + kg * 4;
        #pragma unroll
        for (int nf = 0; nf < 7; ++nf) {
            const int x = nf * 8 + xl;
            if (x < OW) {
                float* o = out + ((size_t)(b * COUT + cob) * OH + y) * OW + x;
                #pragma unroll
                for (int j = 0; j < 4; ++j)
                    o[(size_t)j * OH * OW] = acc[m][nf][j];
            }
        }
    }
}

// ---------------- fp32 fallback (ws too small) ------------------------------
#define COB  16
#define THF  6
#define CIBF 2
#define IRF  (THF + 2)
__global__ __launch_bounds__(256) void conv3x3_fp32(
    const float* __restrict__ img, const float* __restrict__ flt,
    float* __restrict__ out)
{
    __shared__ float si[CIBF][IRF][WW];
    __shared__ float sf[CIBF][COB][9];
    const int tid = threadIdx.x;
    const int tx  = tid & 63;
    const int tg  = tid >> 6;
    int bid = blockIdx.x;
    const int ytile = bid % (OH / THF);  bid /= (OH / THF);
    const int cob   = bid % (COUT / COB); bid /= (COUT / COB);
    const int b     = bid;
    const int y0  = ytile * THF;
    const int co0 = cob * COB;
    float acc[4][THF];
    #pragma unroll
    for (int c = 0; c < 4; ++c)
        #pragma unroll
        for (int y = 0; y < THF; ++y) acc[c][y] = 0.0f;
    for (int ci0 = 0; ci0 < CIN; ci0 += CIBF) {
        for (int i = tid; i < CIBF * IRF * (WW / 4); i += 256) {
            const int cil = i / (IRF * (WW / 4));
            int rem = i - cil * (IRF * (WW / 4));
            const int r = rem / (WW / 4);
            const int v = rem - r * (WW / 4);
            const float4* src = reinterpret_cast<const float4*>(
                img + (((size_t)b * CIN + (ci0 + cil)) * HH + (y0 + r)) * WW) + v;
            reinterpret_cast<float4*>(&si[cil][r][0])[v] = *src;
        }
        for (int i = tid; i < CIBF * COB * 9; i += 256) {
            const int cil = i / (COB * 9);
            int rem = i - cil * (COB * 9);
            const int col = rem / 9;
            const int e   = rem - col * 9;
            sf[cil][col][e] = flt[(((size_t)(co0 + col)) * CIN + (ci0 + cil)) * 9 + e];
        }
        __syncthreads();
        if (tx < OW) {
            #pragma unroll
            for (int cil = 0; cil < CIBF; ++cil) {
                float f[4][9];
                #pragma unroll
                for (int c = 0; c < 4; ++c)
                    #pragma unroll
                    for (int e = 0; e < 9; ++e) f[c][e] = sf[cil][tg * 4 + c][e];
                float a[IRF][3];
                #pragma unroll
                for (int r = 0; r < IRF; ++r) {
                    a[r][0] = si[cil][r][tx + 0];
                    a[r][1] = si[cil][r][tx + 1];
                    a[r][2] = si[cil][r][tx + 2];
                }
                #pragma unroll
                for (int y = 0; y < THF; ++y)
                    #pragma unroll
                    for (int dy = 0; dy < 3; ++dy)
                        #pragma unroll
                        for (int c = 0; c < 4; ++c)
                            acc[c][y] = fmaf(a[y + dy][0], f[c][dy * 3 + 0],
                                        fmaf(a[y + dy][1], f[c][dy * 3 + 1],
                                        fmaf(a[y + dy][2], f[c][dy * 3 + 2], acc[c][y])));
            }
        }
        __syncthreads();
    }
    if (tx < OW) {
        #pragma unroll
        for (int c = 0; c < 4; ++c) {
            const int co = co0 + tg * 4 + c;
            #pragma unroll
            for (int y = 0; y < THF; ++y)
                out[(((size_t)b * COUT + co) * OH + (y0 + y)) * OW + tx] = acc[c][y];
        }
    }
}

extern "C" void kernel_launch(void* const* d_in, const int* in_sizes, int n_in,
                              void* d_out, int out_size, void* d_ws, size_t ws_size,
                              hipStream_t stream) {
    const float* img = (const float*)d_in[0];
    const float* flt = (const float*)d_in[1];
    float* out = (float*)d_out;

    const size_t IMGT_BYTES = (size_t)BB * HH * WW * CIN * 2;
    const size_t FILT_BYTES = (size_t)18 * COUT * CIN * 2;
    if (ws_size < IMGT_BYTES + FILT_BYTES) {
        conv3x3_fp32<<<BB * (COUT / COB) * (OH / THF), 256, 0, stream>>>(img, flt, out);
        return;
    }
    unsigned short* imgT  = (unsigned short*)d_ws;
    unsigned short* filtT = (unsigned short*)((char*)d_ws + IMGT_BYTES);

    prep_img<<<BB * HH, 256, 0, stream>>>(img, imgT);
    prep_flt<<<(COUT * CIN) / 256, 256, 0, stream>>>(flt, filtT);
    conv_mfma<<<4 * 7 * BB, 256, 0, stream>>>(imgT, filtT, out);   // 896 blocks
}

// Round 6
// 232.225 us; speedup vs baseline: 1.1006x; 1.1006x over previous
//
#include <hip/hip_runtime.h>

// Convoluzione: VALID 3x3 cross-correlation, NCHW.
// img [32,128,56,56] f32, filtro [256,128,3,3] f32 -> out [32,256,54,54] f32
// bf16 MFMA implicit shift-conv, filters split hi/lo bf16.
// R6: img LDS double-buffered (1 barrier/c-iter, DMA prefetch c+1 under compute c);
//     filters global->VGPR from L2 (no filter LDS), tap ping-pong via template<C>
//     so ALL register-array indices are compile-time (R5 spilled via runtime parity).

#define BB   32
#define CIN  128
#define COUT 256
#define HH   56
#define WW   56
#define OH   54
#define OW   54

typedef short bf16x8 __attribute__((ext_vector_type(8)));
typedef float f32x4  __attribute__((ext_vector_type(4)));
typedef unsigned short u16x8 __attribute__((ext_vector_type(8)));

#define GLOAD_LDS16(g, l) __builtin_amdgcn_global_load_lds( \
    (const __attribute__((address_space(1))) unsigned int*)(g), \
    (__attribute__((address_space(3))) unsigned int*)(l), 16, 0, 0)

static __device__ __forceinline__ unsigned short f2bf(float f) {
    unsigned int u = __float_as_uint(f);
    u += 0x7FFFu + ((u >> 16) & 1u);
    return (unsigned short)(u >> 16);
}
static __device__ __forceinline__ float bf2f(unsigned short h) {
    return __uint_as_float(((unsigned int)h) << 16);
}

// ---------------- prep 1: img f32 NCHW -> imgT bf16 [b][y][x][ci] ----------
__global__ __launch_bounds__(256) void prep_img(const float* __restrict__ img,
                                                unsigned short* __restrict__ imgT) {
    const int b = blockIdx.x / HH;
    const int y = blockIdx.x - b * HH;
    for (int i = threadIdx.x; i < 16 * WW; i += 256) {
        const int g = i / WW;
        const int x = i - g * WW;
        unsigned short pk[8];
        #pragma unroll
        for (int j = 0; j < 8; ++j)
            pk[j] = f2bf(img[((size_t)(b * CIN + g * 8 + j) * HH + y) * WW + x]);
        *(u16x8*)(imgT + ((size_t)(b * HH + y) * WW + x) * CIN + g * 8) = *(u16x8*)pk;
    }
}

// ---------------- prep 2: filtro f32 OIHW -> filtT bf16 [t*2+p][co][ci] -----
__global__ __launch_bounds__(256) void prep_flt(const float* __restrict__ flt,
                                                unsigned short* __restrict__ filtT) {
    const int idx = blockIdx.x * 256 + threadIdx.x;
    const int co = idx >> 7;
    const int ci = idx & 127;
    float v[9];
    #pragma unroll
    for (int t = 0; t < 9; ++t) v[t] = flt[(size_t)(co * CIN + ci) * 9 + t];
    #pragma unroll
    for (int t = 0; t < 9; ++t) {
        unsigned short h = f2bf(v[t]);
        unsigned short l = f2bf(v[t] - bf2f(h));
        filtT[((size_t)(t * 2 + 0) * COUT + co) * CIN + ci] = h;
        filtT[((size_t)(t * 2 + 1) * COUT + co) * CIN + ci] = l;
    }
}

// ---------------- conv kernel ----------------------------------------------
// Block: 256 thr / 4 waves. Tile: 64 co x 8 rows x 56 cols; wave wv = row pair.
// B (img) LDS double-buffered: per buffer 4 ci-oct planes x 576 sites x 16B.
// A (filters) global->VGPR ping-pong, one tap ahead (L2-resident filtT).
#define IMG_ROWB  896            // 56 sites * 16 B
#define IMG_PLANE 9216           // 576 sites * 16 B (560 used + pad)
#define IMG_BUF   36864          // 4 planes
#define LDS_BYTES 73728          // 2 buffers

template<int C>
static __device__ __forceinline__ void conv_body(
    const unsigned short* __restrict__ imgT,
    const unsigned short* __restrict__ fb,   // per-lane filter base
    const char* __restrict__ bB,             // per-lane B-frag base (buffer 0)
    char* __restrict__ sdst,                 // per-lane stage dst (buffer 0)
    const int (&goff)[9], const bool lane48,
    bf16x8 (&A)[2][8], f32x4 (&acc)[4][7])
{
    constexpr int P = C & 1;                 // tap-parity phase for this c-iter
    __syncthreads();                          // buf[C&1] staged; readers of buf[(C+1)&1] done
    if constexpr (C < 3) {                   // prefetch img chunk C+1 under compute
        char* dst = sdst + ((C + 1) & 1) * IMG_BUF;
        #pragma unroll
        for (int r = 0; r < 9; ++r)
            if (r < 8 || lane48)
                GLOAD_LDS16(imgT + goff[r] + (C + 1) * 32, dst + r * 1024);
    }
    const char* bBc = bB + (C & 1) * IMG_BUF;
    #pragma unroll
    for (int t = 0; t < 9; ++t) {
        const int cur = (P + t) & 1;          // literal after unroll (C,P constexpr)
        const int nxt = cur ^ 1;
        if (t < 8) {                          // prefetch next tap's A (this c)
            #pragma unroll
            for (int m = 0; m < 4; ++m) {
                A[nxt][m*2+0] = *(const bf16x8*)(fb + (size_t)(2*(t+1)+0)*32768 + m*2048 + C*32);
                A[nxt][m*2+1] = *(const bf16x8*)(fb + (size_t)(2*(t+1)+1)*32768 + m*2048 + C*32);
            }
        } else if constexpr (C < 3) {         // prefetch tap 0 of next c
            #pragma unroll
            for (int m = 0; m < 4; ++m) {
                A[nxt][m*2+0] = *(const bf16x8*)(fb + (size_t)0     + m*2048 + (C+1)*32);
                A[nxt][m*2+1] = *(const bf16x8*)(fb + (size_t)32768 + m*2048 + (C+1)*32);
            }
        }
        const int dy = t / 3, dx = t % 3;
        __builtin_amdgcn_s_setprio(1);
        #pragma unroll
        for (int nf = 0; nf < 7; ++nf) {
            bf16x8 bv = *(const bf16x8*)(bBc + dy * IMG_ROWB + (nf * 8 + dx) * 16);
            #pragma unroll
            for (int m = 0; m < 4; ++m) {
                acc[m][nf] = __builtin_amdgcn_mfma_f32_16x16x32_bf16(A[cur][m*2+0], bv, acc[m][nf], 0, 0, 0);
                acc[m][nf] = __builtin_amdgcn_mfma_f32_16x16x32_bf16(A[cur][m*2+1], bv, acc[m][nf], 0, 0, 0);
            }
        }
        __builtin_amdgcn_s_setprio(0);
    }
}

__global__ __launch_bounds__(256, 2) void conv_mfma(
    const unsigned short* __restrict__ imgT,
    const unsigned short* __restrict__ filtT,
    float* __restrict__ out)
{
    __shared__ char lds[LDS_BYTES];

    const int tid  = threadIdx.x;
    const int lane = tid & 63, wv = tid >> 6;
    const int sub  = lane & 15, kg = lane >> 4;
    const int ysub = sub >> 3,  xl = sub & 7;
    const bool lane48 = lane < 48;

    // XCD swizzle (896 = 8*112), cot fastest -> 4 blocks share img tile in L2
    const int w    = (blockIdx.x & 7) * 112 + (blockIdx.x >> 3);
    const int cot  = w & 3;
    const int rest = w >> 2;
    const int strip = rest % 7;
    const int b     = rest / 7;
    const int co0   = cot * 64;
    const int ystart = (strip < 6) ? strip * 8 : (OH - 8);

    char* const pImg = lds;
    const char* bB = pImg + kg * IMG_PLANE + (2 * wv + ysub) * IMG_ROWB + xl * 16;
    char* sdst = pImg + wv * IMG_PLANE + lane * 16;
    // A-frag per-lane base: (tp2, co0+sub+m*16, kg*8 + C*32)
    const unsigned short* fb = filtT + (co0 + sub) * CIN + kg * 8;

    // staging offsets: wave wv stages plane wv; site = r*64+lane
    int goff[9];
    #pragma unroll
    for (int r = 0; r < 9; ++r) {
        const int site = r * 64 + lane;
        const int rr = site / 56;
        const int xx = site - rr * 56;
        goff[r] = ((b * HH + ystart + rr) * WW + xx) * CIN + wv * 8;
    }

    f32x4 acc[4][7];
    #pragma unroll
    for (int m = 0; m < 4; ++m)
        #pragma unroll
        for (int nf = 0; nf < 7; ++nf) acc[m][nf] = (f32x4)0.0f;

    bf16x8 A[2][8];
    #pragma unroll
    for (int m = 0; m < 4; ++m) {                    // preload tap 0, c=0
        A[0][m*2+0] = *(const bf16x8*)(fb + (size_t)0     + m*2048);
        A[0][m*2+1] = *(const bf16x8*)(fb + (size_t)32768 + m*2048);
    }
    {   // STAGE(0)
        #pragma unroll
        for (int r = 0; r < 9; ++r)
            if (r < 8 || lane48)
                GLOAD_LDS16(imgT + goff[r], sdst + r * 1024);
    }

    conv_body<0>(imgT, fb, bB, sdst, goff, lane48, A, acc);
    conv_body<1>(imgT, fb, bB, sdst, goff, lane48, A, acc);
    conv_body<2>(imgT, fb, bB, sdst, goff, lane48, A, acc);
    conv_body<3>(imgT, fb, bB, sdst, goff, lane48, A, acc);

    // epilogue: D col=lane&15 -> spatial, row=kg*4+j -> co
    const int y = ystart + 2 * wv + ysub;
    #pragma unroll
    for (int m = 0; m < 4; ++m) {
        const int cob = co0 + m * 16 + kg * 4;
        #pragma unroll
        for (int nf = 0; nf < 7; ++nf) {
            const int x = nf * 8 + xl;
            if (x < OW) {
                float* o = out + ((size_t)(b * COUT + cob) * OH + y) * OW + x;
                #pragma unroll
                for (int j = 0; j < 4; ++j)
                    o[(size_t)j * OH * OW] = acc[m][nf][j];
            }
        }
    }
}

// ---------------- fp32 fallback (ws too small) ------------------------------
#define COB  16
#define THF  6
#define CIBF 2
#define IRF  (THF + 2)
__global__ __launch_bounds__(256) void conv3x3_fp32(
    const float* __restrict__ img, const float* __restrict__ flt,
    float* __restrict__ out)
{
    __shared__ float si[CIBF][IRF][WW];
    __shared__ float sf[CIBF][COB][9];
    const int tid = threadIdx.x;
    const int tx  = tid & 63;
    const int tg  = tid >> 6;
    int bid = blockIdx.x;
    const int ytile = bid % (OH / THF);  bid /= (OH / THF);
    const int cob   = bid % (COUT / COB); bid /= (COUT / COB);
    const int b     = bid;
    const int y0  = ytile * THF;
    const int co0 = cob * COB;
    float acc[4][THF];
    #pragma unroll
    for (int c = 0; c < 4; ++c)
        #pragma unroll
        for (int y = 0; y < THF; ++y) acc[c][y] = 0.0f;
    for (int ci0 = 0; ci0 < CIN; ci0 += CIBF) {
        for (int i = tid; i < CIBF * IRF * (WW / 4); i += 256) {
            const int cil = i / (IRF * (WW / 4));
            int rem = i - cil * (IRF * (WW / 4));
            const int r = rem / (WW / 4);
            const int v = rem - r * (WW / 4);
            const float4* src = reinterpret_cast<const float4*>(
                img + (((size_t)b * CIN + (ci0 + cil)) * HH + (y0 + r)) * WW) + v;
            reinterpret_cast<float4*>(&si[cil][r][0])[v] = *src;
        }
        for (int i = tid; i < CIBF * COB * 9; i += 256) {
            const int cil = i / (COB * 9);
            int rem = i - cil * (COB * 9);
            const int col = rem / 9;
            const int e   = rem - col * 9;
            sf[cil][col][e] = flt[(((size_t)(co0 + col)) * CIN + (ci0 + cil)) * 9 + e];
        }
        __syncthreads();
        if (tx < OW) {
            #pragma unroll
            for (int cil = 0; cil < CIBF; ++cil) {
                float f[4][9];
                #pragma unroll
                for (int c = 0; c < 4; ++c)
                    #pragma unroll
                    for (int e = 0; e < 9; ++e) f[c][e] = sf[cil][tg * 4 + c][e];
                float a[IRF][3];
                #pragma unroll
                for (int r = 0; r < IRF; ++r) {
                    a[r][0] = si[cil][r][tx + 0];
                    a[r][1] = si[cil][r][tx + 1];
                    a[r][2] = si[cil][r][tx + 2];
                }
                #pragma unroll
                for (int y = 0; y < THF; ++y)
                    #pragma unroll
                    for (int dy = 0; dy < 3; ++dy)
                        #pragma unroll
                        for (int c = 0; c < 4; ++c)
                            acc[c][y] = fmaf(a[y + dy][0], f[c][dy * 3 + 0],
                                        fmaf(a[y + dy][1], f[c][dy * 3 + 1],
                                        fmaf(a[y + dy][2], f[c][dy * 3 + 2], acc[c][y])));
            }
        }
        __syncthreads();
    }
    if (tx < OW) {
        #pragma unroll
        for (int c = 0; c < 4; ++c) {
            const int co = co0 + tg * 4 + c;
            #pragma unroll
            for (int y = 0; y < THF; ++y)
                out[(((size_t)b * COUT + co) * OH + (y0 + y)) * OW + tx] = acc[c][y];
        }
    }
}

extern "C" void kernel_launch(void* const* d_in, const int* in_sizes, int n_in,
                              void* d_out, int out_size, void* d_ws, size_t ws_size,
                              hipStream_t stream) {
    const float* img = (const float*)d_in[0];
    const float* flt = (const float*)d_in[1];
    float* out = (float*)d_out;

    const size_t IMGT_BYTES = (size_t)BB * HH * WW * CIN * 2;
    const size_t FILT_BYTES = (size_t)18 * COUT * CIN * 2;
    if (ws_size < IMGT_BYTES + FILT_BYTES) {
        conv3x3_fp32<<<BB * (COUT / COB) * (OH / THF), 256, 0, stream>>>(img, flt, out);
        return;
    }
    unsigned short* imgT  = (unsigned short*)d_ws;
    unsigned short* filtT = (unsigned short*)((char*)d_ws + IMGT_BYTES);

    prep_img<<<BB * HH, 256, 0, stream>>>(img, imgT);
    prep_flt<<<(COUT * CIN) / 256, 256, 0, stream>>>(flt, filtT);
    conv_mfma<<<4 * 7 * BB, 256, 0, stream>>>(imgT, filtT, out);   // 896 blocks
}

// Round 7
// 188.589 us; speedup vs baseline: 1.3553x; 1.2314x over previous
//
#include <hip/hip_runtime.h>

// Convoluzione: VALID 3x3 cross-correlation, NCHW.
// img [32,128,56,56] f32, filtro [256,128,3,3] f32 -> out [32,256,54,54] f32
// bf16 MFMA implicit shift-conv, filters split hi/lo bf16.
// R7: fix R6's register spill (VGPR=128 cap, 170MB scratch):
//  - filtF layout [cot][t2][sub][m][c][kg][e]: per-lane offset = 1 VGPR,
//    all tap/m/c offsets lane-uniform -> SGPR+imm addressing.
//  - bv bursts split 4+3 with sched_barrier(0) to cap ds_read hoisting.

#define BB   32
#define CIN  128
#define COUT 256
#define HH   56
#define WW   56
#define OH   54
#define OW   54

typedef short bf16x8 __attribute__((ext_vector_type(8)));
typedef float f32x4  __attribute__((ext_vector_type(4)));
typedef unsigned short u16x8 __attribute__((ext_vector_type(8)));

#define GLOAD_LDS16(g, l) __builtin_amdgcn_global_load_lds( \
    (const __attribute__((address_space(1))) unsigned int*)(g), \
    (__attribute__((address_space(3))) unsigned int*)(l), 16, 0, 0)

static __device__ __forceinline__ unsigned short f2bf(float f) {
    unsigned int u = __float_as_uint(f);
    u += 0x7FFFu + ((u >> 16) & 1u);
    return (unsigned short)(u >> 16);
}
static __device__ __forceinline__ float bf2f(unsigned short h) {
    return __uint_as_float(((unsigned int)h) << 16);
}

// ---------------- prep 1: img f32 NCHW -> imgT bf16 [b][y][x][ci] ----------
__global__ __launch_bounds__(256) void prep_img(const float* __restrict__ img,
                                                unsigned short* __restrict__ imgT) {
    const int b = blockIdx.x / HH;
    const int y = blockIdx.x - b * HH;
    for (int i = threadIdx.x; i < 16 * WW; i += 256) {
        const int g = i / WW;
        const int x = i - g * WW;
        unsigned short pk[8];
        #pragma unroll
        for (int j = 0; j < 8; ++j)
            pk[j] = f2bf(img[((size_t)(b * CIN + g * 8 + j) * HH + y) * WW + x]);
        *(u16x8*)(imgT + ((size_t)(b * HH + y) * WW + x) * CIN + g * 8) = *(u16x8*)pk;
    }
}

// ---- prep 2: filtro f32 OIHW -> filtF[cot][t2][sub][m][c][kg][e] bf16 -----
// t2 = 2*t + (0:hi,1:lo); co = cot*64 + m*16 + sub; ci = c*32 + kg*8 + e.
// elem = ((((cot*18 + t2)*16 + sub)*4 + m)*4 + c)*4 + kg)*8 + e
__global__ __launch_bounds__(256) void prep_flt(const float* __restrict__ flt,
                                                unsigned short* __restrict__ filtF) {
    const int idx = blockIdx.x * 256 + threadIdx.x;   // 0..32767
    const int co = idx >> 7;
    const int ci = idx & 127;
    const int cot = co >> 6, col = co & 63;
    const int m = col >> 4, sub = col & 15;
    const int c = ci >> 5, kg = (ci >> 3) & 3, e = ci & 7;
    float v[9];
    #pragma unroll
    for (int t = 0; t < 9; ++t) v[t] = flt[(size_t)(co * CIN + ci) * 9 + t];
    #pragma unroll
    for (int t = 0; t < 9; ++t) {
        unsigned short h = f2bf(v[t]);
        unsigned short l = f2bf(v[t] - bf2f(h));
        const size_t base = (size_t)(cot * 18) * 8192 + (size_t)sub * 512
                          + m * 128 + c * 32 + kg * 8 + e;
        filtF[base + (2 * t + 0) * 8192] = h;
        filtF[base + (2 * t + 1) * 8192] = l;
    }
}

// ---------------- conv kernel ----------------------------------------------
// Block: 256 thr / 4 waves. Tile: 64 co x 8 rows x 56 cols; wave wv = row pair.
// B (img) LDS double-buffered. A (filters) global->VGPR ping-pong from L1/L2.
#define IMG_ROWB  896            // 56 sites * 16 B
#define IMG_PLANE 9216           // 576 sites * 16 B (560 used + pad)
#define IMG_BUF   36864          // 4 planes
#define LDS_BYTES 73728          // 2 buffers

template<int C>
static __device__ __forceinline__ void conv_body(
    const unsigned short* __restrict__ imgT,
    const unsigned short* __restrict__ fbF,  // filtF + cot*147456 (uniform)
    const int laneoff,                       // per-lane: sub*512 + kg*8 elems
    const char* __restrict__ bB,
    char* __restrict__ sdst,
    const int (&goff)[9], const bool lane48,
    bf16x8 (&A)[2][8], f32x4 (&acc)[4][7])
{
    constexpr int P = C & 1;
    __syncthreads();
    if constexpr (C < 3) {
        char* dst = sdst + ((C + 1) & 1) * IMG_BUF;
        #pragma unroll
        for (int r = 0; r < 9; ++r)
            if (r < 8 || lane48)
                GLOAD_LDS16(imgT + goff[r] + (C + 1) * 32, dst + r * 1024);
    }
    const char* bBc = bB + (C & 1) * IMG_BUF;
    #pragma unroll
    for (int t = 0; t < 9; ++t) {
        const int cur = (P + t) & 1;          // literal after unroll
        const int nxt = cur ^ 1;
        if (t < 8) {
            #pragma unroll
            for (int m = 0; m < 4; ++m) {
                A[nxt][m*2+0] = *(const bf16x8*)(fbF + laneoff + (2*(t+1)+0)*8192 + m*128 + C*32);
                A[nxt][m*2+1] = *(const bf16x8*)(fbF + laneoff + (2*(t+1)+1)*8192 + m*128 + C*32);
            }
        } else if constexpr (C < 3) {
            #pragma unroll
            for (int m = 0; m < 4; ++m) {
                A[nxt][m*2+0] = *(const bf16x8*)(fbF + laneoff + 0    + m*128 + (C+1)*32);
                A[nxt][m*2+1] = *(const bf16x8*)(fbF + laneoff + 8192 + m*128 + (C+1)*32);
            }
        }
        const int dy = t / 3, dx = t % 3;
        __builtin_amdgcn_s_setprio(1);
        #pragma unroll
        for (int nf = 0; nf < 4; ++nf) {       // first half: bv0-3
            bf16x8 bv = *(const bf16x8*)(bBc + dy * IMG_ROWB + (nf * 8 + dx) * 16);
            #pragma unroll
            for (int m = 0; m < 4; ++m) {
                acc[m][nf] = __builtin_amdgcn_mfma_f32_16x16x32_bf16(A[cur][m*2+0], bv, acc[m][nf], 0, 0, 0);
                acc[m][nf] = __builtin_amdgcn_mfma_f32_16x16x32_bf16(A[cur][m*2+1], bv, acc[m][nf], 0, 0, 0);
            }
        }
        __builtin_amdgcn_sched_barrier(0);     // cap bv live-range (reg pressure)
        #pragma unroll
        for (int nf = 4; nf < 7; ++nf) {       // second half: bv4-6
            bf16x8 bv = *(const bf16x8*)(bBc + dy * IMG_ROWB + (nf * 8 + dx) * 16);
            #pragma unroll
            for (int m = 0; m < 4; ++m) {
                acc[m][nf] = __builtin_amdgcn_mfma_f32_16x16x32_bf16(A[cur][m*2+0], bv, acc[m][nf], 0, 0, 0);
                acc[m][nf] = __builtin_amdgcn_mfma_f32_16x16x32_bf16(A[cur][m*2+1], bv, acc[m][nf], 0, 0, 0);
            }
        }
        __builtin_amdgcn_s_setprio(0);
    }
}

__global__ __launch_bounds__(256, 2) void conv_mfma(
    const unsigned short* __restrict__ imgT,
    const unsigned short* __restrict__ filtF,
    float* __restrict__ out)
{
    __shared__ char lds[LDS_BYTES];

    const int tid  = threadIdx.x;
    const int lane = tid & 63, wv = tid >> 6;
    const int sub  = lane & 15, kg = lane >> 4;
    const int ysub = sub >> 3,  xl = sub & 7;
    const bool lane48 = lane < 48;

    // XCD swizzle (896 = 8*112), cot fastest -> 4 blocks share img tile in L2
    const int w    = (blockIdx.x & 7) * 112 + (blockIdx.x >> 3);
    const int cot  = w & 3;
    const int rest = w >> 2;
    const int strip = rest % 7;
    const int b     = rest / 7;
    const int co0   = cot * 64;
    const int ystart = (strip < 6) ? strip * 8 : (OH - 8);

    char* const pImg = lds;
    const char* bB = pImg + kg * IMG_PLANE + (2 * wv + ysub) * IMG_ROWB + xl * 16;
    char* sdst = pImg + wv * IMG_PLANE + lane * 16;

    const unsigned short* fbF = filtF + (size_t)cot * 147456;
    const int laneoff = sub * 512 + kg * 8;      // single per-lane VGPR

    int goff[9];
    #pragma unroll
    for (int r = 0; r < 9; ++r) {
        const int site = r * 64 + lane;
        const int rr = site / 56;
        const int xx = site - rr * 56;
        goff[r] = ((b * HH + ystart + rr) * WW + xx) * CIN + wv * 8;
    }

    f32x4 acc[4][7];
    #pragma unroll
    for (int m = 0; m < 4; ++m)
        #pragma unroll
        for (int nf = 0; nf < 7; ++nf) acc[m][nf] = (f32x4)0.0f;

    bf16x8 A[2][8];
    #pragma unroll
    for (int m = 0; m < 4; ++m) {                // preload tap 0, c=0
        A[0][m*2+0] = *(const bf16x8*)(fbF + laneoff + 0    + m*128);
        A[0][m*2+1] = *(const bf16x8*)(fbF + laneoff + 8192 + m*128);
    }
    {   // STAGE(0)
        #pragma unroll
        for (int r = 0; r < 9; ++r)
            if (r < 8 || lane48)
                GLOAD_LDS16(imgT + goff[r], sdst + r * 1024);
    }

    conv_body<0>(imgT, fbF, laneoff, bB, sdst, goff, lane48, A, acc);
    conv_body<1>(imgT, fbF, laneoff, bB, sdst, goff, lane48, A, acc);
    conv_body<2>(imgT, fbF, laneoff, bB, sdst, goff, lane48, A, acc);
    conv_body<3>(imgT, fbF, laneoff, bB, sdst, goff, lane48, A, acc);

    // epilogue: D col=lane&15 -> spatial, row=kg*4+j -> co
    const int y = ystart + 2 * wv + ysub;
    #pragma unroll
    for (int m = 0; m < 4; ++m) {
        const int cob = co0 + m * 16 + kg * 4;
        #pragma unroll
        for (int nf = 0; nf < 7; ++nf) {
            const int x = nf * 8 + xl;
            if (x < OW) {
                float* o = out + ((size_t)(b * COUT + cob) * OH + y) * OW + x;
                #pragma unroll
                for (int j = 0; j < 4; ++j)
                    o[(size_t)j * OH * OW] = acc[m][nf][j];
            }
        }
    }
}

// ---------------- fp32 fallback (ws too small) ------------------------------
#define COB  16
#define THF  6
#define CIBF 2
#define IRF  (THF + 2)
__global__ __launch_bounds__(256) void conv3x3_fp32(
    const float* __restrict__ img, const float* __restrict__ flt,
    float* __restrict__ out)
{
    __shared__ float si[CIBF][IRF][WW];
    __shared__ float sf[CIBF][COB][9];
    const int tid = threadIdx.x;
    const int tx  = tid & 63;
    const int tg  = tid >> 6;
    int bid = blockIdx.x;
    const int ytile = bid % (OH / THF);  bid /= (OH / THF);
    const int cob   = bid % (COUT / COB); bid /= (COUT / COB);
    const int b     = bid;
    const int y0  = ytile * THF;
    const int co0 = cob * COB;
    float acc[4][THF];
    #pragma unroll
    for (int c = 0; c < 4; ++c)
        #pragma unroll
        for (int y = 0; y < THF; ++y) acc[c][y] = 0.0f;
    for (int ci0 = 0; ci0 < CIN; ci0 += CIBF) {
        for (int i = tid; i < CIBF * IRF * (WW / 4); i += 256) {
            const int cil = i / (IRF * (WW / 4));
            int rem = i - cil * (IRF * (WW / 4));
            const int r = rem / (WW / 4);
            const int v = rem - r * (WW / 4);
            const float4* src = reinterpret_cast<const float4*>(
                img + (((size_t)b * CIN + (ci0 + cil)) * HH + (y0 + r)) * WW) + v;
            reinterpret_cast<float4*>(&si[cil][r][0])[v] = *src;
        }
        for (int i = tid; i < CIBF * COB * 9; i += 256) {
            const int cil = i / (COB * 9);
            int rem = i - cil * (COB * 9);
            const int col = rem / 9;
            const int e   = rem - col * 9;
            sf[cil][col][e] = flt[(((size_t)(co0 + col)) * CIN + (ci0 + cil)) * 9 + e];
        }
        __syncthreads();
        if (tx < OW) {
            #pragma unroll
            for (int cil = 0; cil < CIBF; ++cil) {
                float f[4][9];
                #pragma unroll
                for (int c = 0; c < 4; ++c)
                    #pragma unroll
                    for (int e = 0; e < 9; ++e) f[c][e] = sf[cil][tg * 4 + c][e];
                float a[IRF][3];
                #pragma unroll
                for (int r = 0; r < IRF; ++r) {
                    a[r][0] = si[cil][r][tx + 0];
                    a[r][1] = si[cil][r][tx + 1];
                    a[r][2] = si[cil][r][tx + 2];
                }
                #pragma unroll
                for (int y = 0; y < THF; ++y)
                    #pragma unroll
                    for (int dy = 0; dy < 3; ++dy)
                        #pragma unroll
                        for (int c = 0; c < 4; ++c)
                            acc[c][y] = fmaf(a[y + dy][0], f[c][dy * 3 + 0],
                                        fmaf(a[y + dy][1], f[c][dy * 3 + 1],
                                        fmaf(a[y + dy][2], f[c][dy * 3 + 2], acc[c][y])));
            }
        }
        __syncthreads();
    }
    if (tx < OW) {
        #pragma unroll
        for (int c = 0; c < 4; ++c) {
            const int co = co0 + tg * 4 + c;
            #pragma unroll
            for (int y = 0; y < THF; ++y)
                out[(((size_t)b * COUT + co) * OH + (y0 + y)) * OW + tx] = acc[c][y];
        }
    }
}

extern "C" void kernel_launch(void* const* d_in, const int* in_sizes, int n_in,
                              void* d_out, int out_size, void* d_ws, size_t ws_size,
                              hipStream_t stream) {
    const float* img = (const float*)d_in[0];
    const float* flt = (const float*)d_in[1];
    float* out = (float*)d_out;

    const size_t IMGT_BYTES = (size_t)BB * HH * WW * CIN * 2;
    const size_t FILT_BYTES = (size_t)18 * COUT * CIN * 2;
    if (ws_size < IMGT_BYTES + FILT_BYTES) {
        conv3x3_fp32<<<BB * (COUT / COB) * (OH / THF), 256, 0, stream>>>(img, flt, out);
        return;
    }
    unsigned short* imgT  = (unsigned short*)d_ws;
    unsigned short* filtF = (unsigned short*)((char*)d_ws + IMGT_BYTES);

    prep_img<<<BB * HH, 256, 0, stream>>>(img, imgT);
    prep_flt<<<(COUT * CIN) / 256, 256, 0, stream>>>(flt, filtF);
    conv_mfma<<<4 * 7 * BB, 256, 0, stream>>>(imgT, filtF, out);   // 896 blocks
}

// Round 8
// 149.645 us; speedup vs baseline: 1.7080x; 1.2602x over previous
//
#include <hip/hip_runtime.h>

// Convoluzione: VALID 3x3 cross-correlation, NCHW.
// img [32,128,56,56] f32, filtro [256,128,3,3] f32 -> out [32,256,54,54] f32
// bf16 MFMA implicit shift-conv, filters split hi/lo bf16.
// R8: filters back in LDS (broadcast, kills R7's 4x-redundant VMEM A-traffic)
//     but fully phase-buffered: img 2-buf + filter A/B tap-half regions, DMA
//     always issued one phase before its consuming barrier -> drain never
//     exposed. 1 block/CU, 144KB LDS, launch_bounds(256,1) -> no VGPR cap.

#define BB   32
#define CIN  128
#define COUT 256
#define HH   56
#define WW   56
#define OH   54
#define OW   54

typedef short bf16x8 __attribute__((ext_vector_type(8)));
typedef float f32x4  __attribute__((ext_vector_type(4)));
typedef unsigned short u16x8 __attribute__((ext_vector_type(8)));

#define GLOAD_LDS16(g, l) __builtin_amdgcn_global_load_lds( \
    (const __attribute__((address_space(1))) unsigned int*)(g), \
    (__attribute__((address_space(3))) unsigned int*)(l), 16, 0, 0)

static __device__ __forceinline__ unsigned short f2bf(float f) {
    unsigned int u = __float_as_uint(f);
    u += 0x7FFFu + ((u >> 16) & 1u);
    return (unsigned short)(u >> 16);
}
static __device__ __forceinline__ float bf2f(unsigned short h) {
    return __uint_as_float(((unsigned int)h) << 16);
}

// ---------------- prep 1: img f32 NCHW -> imgT bf16 [b][y][x][ci] ----------
__global__ __launch_bounds__(256) void prep_img(const float* __restrict__ img,
                                                unsigned short* __restrict__ imgT) {
    const int b = blockIdx.x / HH;
    const int y = blockIdx.x - b * HH;
    for (int i = threadIdx.x; i < 16 * WW; i += 256) {
        const int g = i / WW;
        const int x = i - g * WW;
        unsigned short pk[8];
        #pragma unroll
        for (int j = 0; j < 8; ++j)
            pk[j] = f2bf(img[((size_t)(b * CIN + g * 8 + j) * HH + y) * WW + x]);
        *(u16x8*)(imgT + ((size_t)(b * HH + y) * WW + x) * CIN + g * 8) = *(u16x8*)pk;
    }
}

// ---- prep 2: filtro f32 OIHW -> filtF[cot][t2][sub][m][c][kg][e] bf16 -----
// t2 = 2*t + (0:hi,1:lo); co = cot*64 + m*16 + sub; ci = c*32 + kg*8 + e.
__global__ __launch_bounds__(256) void prep_flt(const float* __restrict__ flt,
                                                unsigned short* __restrict__ filtF) {
    const int idx = blockIdx.x * 256 + threadIdx.x;   // 0..32767
    const int co = idx >> 7;
    const int ci = idx & 127;
    const int cot = co >> 6, col = co & 63;
    const int m = col >> 4, sub = col & 15;
    const int c = ci >> 5, kg = (ci >> 3) & 3, e = ci & 7;
    float v[9];
    #pragma unroll
    for (int t = 0; t < 9; ++t) v[t] = flt[(size_t)(co * CIN + ci) * 9 + t];
    #pragma unroll
    for (int t = 0; t < 9; ++t) {
        unsigned short h = f2bf(v[t]);
        unsigned short l = f2bf(v[t] - bf2f(h));
        const size_t base = (size_t)(cot * 18) * 8192 + (size_t)sub * 512
                          + m * 128 + c * 32 + kg * 8 + e;
        filtF[base + (2 * t + 0) * 8192] = h;
        filtF[base + (2 * t + 1) * 8192] = l;
    }
}

// ---------------- conv kernel ----------------------------------------------
// Block: 256 thr / 4 waves, 1 block/CU. Tile: 64 co x 8 rows x 56 cols.
// LDS: img 2 x (4 planes x 576 sites x 16B)      = 73728
//      fltA (taps0-4) 4 planes x 10 t2 x 64co x16 = 40960
//      fltB (taps5-8) 4 planes x  8 t2 x 64co x16 = 32768   total 147456
#define IMG_ROWB   896           // 56 sites * 16 B
#define IMG_PLANE  9216          // 576 sites * 16 B (560 used + pad)
#define IMG_BUF    36864
#define FLTA_OFF   73728
#define FLTA_PLANE 10240
#define FLTB_OFF   114688
#define FLTB_PLANE 8192
#define LDS_BYTES  147456

// compute taps [T0,T1): A-frags from aBase (slot (t-T0)*2 + hl), B from bBc
template<int T0, int T1>
static __device__ __forceinline__ void compute_taps(const char* __restrict__ aBase,
                                                    const char* __restrict__ bBc,
                                                    f32x4 (&acc)[4][7]) {
    #pragma unroll
    for (int t = T0; t < T1; ++t) {
        const int dy = t / 3, dx = t % 3;
        const int sl = (t - T0) * 2;
        bf16x8 ah[4], al[4];
        #pragma unroll
        for (int m = 0; m < 4; ++m) {
            ah[m] = *(const bf16x8*)(aBase + (sl + 0) * 1024 + m * 256);
            al[m] = *(const bf16x8*)(aBase + (sl + 1) * 1024 + m * 256);
        }
        #pragma unroll
        for (int nf = 0; nf < 7; ++nf) {
            bf16x8 bv = *(const bf16x8*)(bBc + dy * IMG_ROWB + (nf * 8 + dx) * 16);
            #pragma unroll
            for (int m = 0; m < 4; ++m) {
                acc[m][nf] = __builtin_amdgcn_mfma_f32_16x16x32_bf16(ah[m], bv, acc[m][nf], 0, 0, 0);
                acc[m][nf] = __builtin_amdgcn_mfma_f32_16x16x32_bf16(al[m], bv, acc[m][nf], 0, 0, 0);
            }
        }
    }
}

template<int C>
static __device__ __forceinline__ void conv_iter(
    const unsigned short* __restrict__ imgT,
    const unsigned short* __restrict__ fsrc,   // per-lane filter stage src base
    char* __restrict__ pImg, char* __restrict__ pFltA, char* __restrict__ pFltB,
    const char* __restrict__ bB, const char* __restrict__ aA, const char* __restrict__ aB,
    const int (&goff)[9], const bool lane48, const int wv, const int lane,
    f32x4 (&acc)[4][7])
{
    // ---- phase 1: [img(C), fltA(C) ready] ----
    {   // DMA: fltB(C); img(C+1)
        char* d = pFltB + wv * FLTB_PLANE + lane * 16;
        #pragma unroll
        for (int t2 = 0; t2 < 8; ++t2)
            GLOAD_LDS16(fsrc + (t2 + 10) * 8192 + C * 32, d + t2 * 1024);
    }
    if constexpr (C < 3) {
        char* d = pImg + ((C + 1) & 1) * IMG_BUF + wv * IMG_PLANE + lane * 16;
        #pragma unroll
        for (int r = 0; r < 9; ++r)
            if (r < 8 || lane48)
                GLOAD_LDS16(imgT + goff[r] + (C + 1) * 32, d + r * 1024);
    }
    compute_taps<0, 5>(aA, bB + (C & 1) * IMG_BUF, acc);
    __syncthreads();
    // ---- phase 2: [fltB(C) ready] ----
    if constexpr (C < 3) {
        char* d = pFltA + wv * FLTA_PLANE + lane * 16;
        #pragma unroll
        for (int t2 = 0; t2 < 10; ++t2)
            GLOAD_LDS16(fsrc + t2 * 8192 + (C + 1) * 32, d + t2 * 1024);
    }
    compute_taps<5, 9>(aB, bB + (C & 1) * IMG_BUF, acc);
    __syncthreads();
}

__global__ __launch_bounds__(256, 1) void conv_mfma(
    const unsigned short* __restrict__ imgT,
    const unsigned short* __restrict__ filtF,
    float* __restrict__ out)
{
    __shared__ char lds[LDS_BYTES];

    const int tid  = threadIdx.x;
    const int lane = tid & 63, wv = tid >> 6;
    const int sub  = lane & 15, kg = lane >> 4;
    const int ysub = sub >> 3,  xl = sub & 7;
    const bool lane48 = lane < 48;

    // XCD swizzle (896 = 8*112), cot fastest -> 4 blocks share img tile in L2
    const int w    = (blockIdx.x & 7) * 112 + (blockIdx.x >> 3);
    const int cot  = w & 3;
    const int rest = w >> 2;
    const int strip = rest % 7;
    const int b     = rest / 7;
    const int co0   = cot * 64;
    const int ystart = (strip < 6) ? strip * 8 : (OH - 8);

    char* const pImg  = lds;
    char* const pFltA = lds + FLTA_OFF;
    char* const pFltB = lds + FLTB_OFF;
    const char* bB = pImg + kg * IMG_PLANE + (2 * wv + ysub) * IMG_ROWB + xl * 16;
    const char* aA = pFltA + kg * FLTA_PLANE + sub * 16;   // + slot*1024 + m*256
    const char* aB = pFltB + kg * FLTB_PLANE + sub * 16;
    // filter stage src: per-lane base; + t2*8192 + c*32
    const unsigned short* fsrc = filtF + (size_t)cot * 147456
                               + (lane & 15) * 512 + (lane >> 4) * 128 + wv * 8;

    int goff[9];
    #pragma unroll
    for (int r = 0; r < 9; ++r) {
        const int site = r * 64 + lane;
        const int rr = site / 56;
        const int xx = site - rr * 56;
        goff[r] = ((b * HH + ystart + rr) * WW + xx) * CIN + wv * 8;
    }

    f32x4 acc[4][7];
    #pragma unroll
    for (int m = 0; m < 4; ++m)
        #pragma unroll
        for (int nf = 0; nf < 7; ++nf) acc[m][nf] = (f32x4)0.0f;

    // prologue: stage img(0) + fltA(0)
    {
        char* d = pImg + wv * IMG_PLANE + lane * 16;
        #pragma unroll
        for (int r = 0; r < 9; ++r)
            if (r < 8 || lane48)
                GLOAD_LDS16(imgT + goff[r], d + r * 1024);
    }
    {
        char* d = pFltA + wv * FLTA_PLANE + lane * 16;
        #pragma unroll
        for (int t2 = 0; t2 < 10; ++t2)
            GLOAD_LDS16(fsrc + t2 * 8192, d + t2 * 1024);
    }
    __syncthreads();

    conv_iter<0>(imgT, fsrc, pImg, pFltA, pFltB, bB, aA, aB, goff, lane48, wv, lane, acc);
    conv_iter<1>(imgT, fsrc, pImg, pFltA, pFltB, bB, aA, aB, goff, lane48, wv, lane, acc);
    conv_iter<2>(imgT, fsrc, pImg, pFltA, pFltB, bB, aA, aB, goff, lane48, wv, lane, acc);
    conv_iter<3>(imgT, fsrc, pImg, pFltA, pFltB, bB, aA, aB, goff, lane48, wv, lane, acc);

    // epilogue: D col=lane&15 -> spatial, row=kg*4+j -> co
    const int y = ystart + 2 * wv + ysub;
    #pragma unroll
    for (int m = 0; m < 4; ++m) {
        const int cob = co0 + m * 16 + kg * 4;
        #pragma unroll
        for (int nf = 0; nf < 7; ++nf) {
            const int x = nf * 8 + xl;
            if (x < OW) {
                float* o = out + ((size_t)(b * COUT + cob) * OH + y) * OW + x;
                #pragma unroll
                for (int j = 0; j < 4; ++j)
                    o[(size_t)j * OH * OW] = acc[m][nf][j];
            }
        }
    }
}

// ---------------- fp32 fallback (ws too small) ------------------------------
#define COB  16
#define THF  6
#define CIBF 2
#define IRF  (THF + 2)
__global__ __launch_bounds__(256) void conv3x3_fp32(
    const float* __restrict__ img, const float* __restrict__ flt,
    float* __restrict__ out)
{
    __shared__ float si[CIBF][IRF][WW];
    __shared__ float sf[CIBF][COB][9];
    const int tid = threadIdx.x;
    const int tx  = tid & 63;
    const int tg  = tid >> 6;
    int bid = blockIdx.x;
    const int ytile = bid % (OH / THF);  bid /= (OH / THF);
    const int cob   = bid % (COUT / COB); bid /= (COUT / COB);
    const int b     = bid;
    const int y0  = ytile * THF;
    const int co0 = cob * COB;
    float acc[4][THF];
    #pragma unroll
    for (int c = 0; c < 4; ++c)
        #pragma unroll
        for (int y = 0; y < THF; ++y) acc[c][y] = 0.0f;
    for (int ci0 = 0; ci0 < CIN; ci0 += CIBF) {
        for (int i = tid; i < CIBF * IRF * (WW / 4); i += 256) {
            const int cil = i / (IRF * (WW / 4));
            int rem = i - cil * (IRF * (WW / 4));
            const int r = rem / (WW / 4);
            const int v = rem - r * (WW / 4);
            const float4* src = reinterpret_cast<const float4*>(
                img + (((size_t)b * CIN + (ci0 + cil)) * HH + (y0 + r)) * WW) + v;
            reinterpret_cast<float4*>(&si[cil][r][0])[v] = *src;
        }
        for (int i = tid; i < CIBF * COB * 9; i += 256) {
            const int cil = i / (COB * 9);
            int rem = i - cil * (COB * 9);
            const int col = rem / 9;
            const int e   = rem - col * 9;
            sf[cil][col][e] = flt[(((size_t)(co0 + col)) * CIN + (ci0 + cil)) * 9 + e];
        }
        __syncthreads();
        if (tx < OW) {
            #pragma unroll
            for (int cil = 0; cil < CIBF; ++cil) {
                float f[4][9];
                #pragma unroll
                for (int c = 0; c < 4; ++c)
                    #pragma unroll
                    for (int e = 0; e < 9; ++e) f[c][e] = sf[cil][tg * 4 + c][e];
                float a[IRF][3];
                #pragma unroll
                for (int r = 0; r < IRF; ++r) {
                    a[r][0] = si[cil][r][tx + 0];
                    a[r][1] = si[cil][r][tx + 1];
                    a[r][2] = si[cil][r][tx + 2];
                }
                #pragma unroll
                for (int y = 0; y < THF; ++y)
                    #pragma unroll
                    for (int dy = 0; dy < 3; ++dy)
                        #pragma unroll
                        for (int c = 0; c < 4; ++c)
                            acc[c][y] = fmaf(a[y + dy][0], f[c][dy * 3 + 0],
                                        fmaf(a[y + dy][1], f[c][dy * 3 + 1],
                                        fmaf(a[y + dy][2], f[c][dy * 3 + 2], acc[c][y])));
            }
        }
        __syncthreads();
    }
    if (tx < OW) {
        #pragma unroll
        for (int c = 0; c < 4; ++c) {
            const int co = co0 + tg * 4 + c;
            #pragma unroll
            for (int y = 0; y < THF; ++y)
                out[(((size_t)b * COUT + co) * OH + (y0 + y)) * OW + tx] = acc[c][y];
        }
    }
}

extern "C" void kernel_launch(void* const* d_in, const int* in_sizes, int n_in,
                              void* d_out, int out_size, void* d_ws, size_t ws_size,
                              hipStream_t stream) {
    const float* img = (const float*)d_in[0];
    const float* flt = (const float*)d_in[1];
    float* out = (float*)d_out;

    const size_t IMGT_BYTES = (size_t)BB * HH * WW * CIN * 2;
    const size_t FILT_BYTES = (size_t)18 * COUT * CIN * 2;
    if (ws_size < IMGT_BYTES + FILT_BYTES) {
        conv3x3_fp32<<<BB * (COUT / COB) * (OH / THF), 256, 0, stream>>>(img, flt, out);
        return;
    }
    unsigned short* imgT  = (unsigned short*)d_ws;
    unsigned short* filtF = (unsigned short*)((char*)d_ws + IMGT_BYTES);

    prep_img<<<BB * HH, 256, 0, stream>>>(img, imgT);
    prep_flt<<<(COUT * CIN) / 256, 256, 0, stream>>>(flt, filtF);
    conv_mfma<<<4 * 7 * BB, 256, 0, stream>>>(imgT, filtF, out);   // 896 blocks
}

// Round 9
// 147.727 us; speedup vs baseline: 1.7302x; 1.0130x over previous
//
#include <hip/hip_runtime.h>

// Convoluzione: VALID 3x3 cross-correlation, NCHW.
// img [32,128,56,56] f32, filtro [256,128,3,3] f32 -> out [32,256,54,54] f32
// bf16 MFMA implicit shift-conv, filters split hi/lo bf16.
// R9: R8's phase-buffered schedule unchanged, but 512 threads / 8 waves
//     (2 waves/SIMD) so MFMA issue gaps + ds_read latency are hidden by TLP.
//     wave = (rowpair rp, m-half mh); staging rounds split by mh; all register
//     indices compile-time (no runtime-indexed arrays -> no scratch).

#define BB   32
#define CIN  128
#define COUT 256
#define HH   56
#define WW   56
#define OH   54
#define OW   54

typedef short bf16x8 __attribute__((ext_vector_type(8)));
typedef float f32x4  __attribute__((ext_vector_type(4)));
typedef unsigned short u16x8 __attribute__((ext_vector_type(8)));

#define GLOAD_LDS16(g, l) __builtin_amdgcn_global_load_lds( \
    (const __attribute__((address_space(1))) unsigned int*)(g), \
    (__attribute__((address_space(3))) unsigned int*)(l), 16, 0, 0)

static __device__ __forceinline__ unsigned short f2bf(float f) {
    unsigned int u = __float_as_uint(f);
    u += 0x7FFFu + ((u >> 16) & 1u);
    return (unsigned short)(u >> 16);
}
static __device__ __forceinline__ float bf2f(unsigned short h) {
    return __uint_as_float(((unsigned int)h) << 16);
}

// ---------------- prep 1: img f32 NCHW -> imgT bf16 [b][y][x][ci] ----------
__global__ __launch_bounds__(256) void prep_img(const float* __restrict__ img,
                                                unsigned short* __restrict__ imgT) {
    const int b = blockIdx.x / HH;
    const int y = blockIdx.x - b * HH;
    for (int i = threadIdx.x; i < 16 * WW; i += 256) {
        const int g = i / WW;
        const int x = i - g * WW;
        unsigned short pk[8];
        #pragma unroll
        for (int j = 0; j < 8; ++j)
            pk[j] = f2bf(img[((size_t)(b * CIN + g * 8 + j) * HH + y) * WW + x]);
        *(u16x8*)(imgT + ((size_t)(b * HH + y) * WW + x) * CIN + g * 8) = *(u16x8*)pk;
    }
}

// ---- prep 2: filtro f32 OIHW -> filtF[cot][t2][sub][m][c][kg][e] bf16 -----
// t2 = 2*t + (0:hi,1:lo); co = cot*64 + m*16 + sub; ci = c*32 + kg*8 + e.
__global__ __launch_bounds__(256) void prep_flt(const float* __restrict__ flt,
                                                unsigned short* __restrict__ filtF) {
    const int idx = blockIdx.x * 256 + threadIdx.x;   // 0..32767
    const int co = idx >> 7;
    const int ci = idx & 127;
    const int cot = co >> 6, col = co & 63;
    const int m = col >> 4, sub = col & 15;
    const int c = ci >> 5, kg = (ci >> 3) & 3, e = ci & 7;
    float v[9];
    #pragma unroll
    for (int t = 0; t < 9; ++t) v[t] = flt[(size_t)(co * CIN + ci) * 9 + t];
    #pragma unroll
    for (int t = 0; t < 9; ++t) {
        unsigned short h = f2bf(v[t]);
        unsigned short l = f2bf(v[t] - bf2f(h));
        const size_t base = (size_t)(cot * 18) * 8192 + (size_t)sub * 512
                          + m * 128 + c * 32 + kg * 8 + e;
        filtF[base + (2 * t + 0) * 8192] = h;
        filtF[base + (2 * t + 1) * 8192] = l;
    }
}

// ---------------- conv kernel ----------------------------------------------
// Block: 512 thr / 8 waves, 1 block/CU (LDS 144KB). Tile: 64co x 8rows x 56cols.
// wave w: rp = w>>1 (rowpair), mh = w&1 (m-half: m = mh*2 + mm).
// LDS: img 2 x (4 planes x 576 sites x 16B) = 73728
//      fltA (taps0-4) 4 x 10 t2 x 64co x 16  = 40960
//      fltB (taps5-8) 4 x  8 t2 x 64co x 16  = 32768    total 147456
#define IMG_ROWB   896
#define IMG_PLANE  9216
#define IMG_BUF    36864
#define FLTA_OFF   73728
#define FLTA_PLANE 10240
#define FLTB_OFF   114688
#define FLTB_PLANE 8192
#define LDS_BYTES  147456

// compute taps [T0,T1): A from aBase (+ (sl+h)*1024 + mm*256), B from bBc
template<int T0, int T1>
static __device__ __forceinline__ void compute_taps(const char* __restrict__ aBase,
                                                    const char* __restrict__ bBc,
                                                    f32x4 (&acc)[2][7]) {
    #pragma unroll
    for (int t = T0; t < T1; ++t) {
        const int dy = t / 3, dx = t % 3;
        const int sl = (t - T0) * 2;
        bf16x8 ah[2], al[2];
        #pragma unroll
        for (int mm = 0; mm < 2; ++mm) {
            ah[mm] = *(const bf16x8*)(aBase + (sl + 0) * 1024 + mm * 256);
            al[mm] = *(const bf16x8*)(aBase + (sl + 1) * 1024 + mm * 256);
        }
        #pragma unroll
        for (int nf = 0; nf < 7; ++nf) {
            bf16x8 bv = *(const bf16x8*)(bBc + dy * IMG_ROWB + (nf * 8 + dx) * 16);
            #pragma unroll
            for (int mm = 0; mm < 2; ++mm) {
                acc[mm][nf] = __builtin_amdgcn_mfma_f32_16x16x32_bf16(ah[mm], bv, acc[mm][nf], 0, 0, 0);
                acc[mm][nf] = __builtin_amdgcn_mfma_f32_16x16x32_bf16(al[mm], bv, acc[mm][nf], 0, 0, 0);
            }
        }
    }
}

template<int C>
static __device__ __forceinline__ void conv_iter(
    const unsigned short* __restrict__ imgT,
    const unsigned short* __restrict__ fsrcA,  // + j*8192 + c*32  (j=0..4)
    const unsigned short* __restrict__ fsrcB,  // + j*8192 + c*32  (j=0..3)
    char* __restrict__ sdstI,                  // img dst base (buf0), + k*1024
    char* __restrict__ fdstA,                  // fltA dst base, + j*1024
    char* __restrict__ fdstB,                  // fltB dst base, + j*1024
    const char* __restrict__ bB, const char* __restrict__ aA, const char* __restrict__ aB,
    const int (&gsite)[5],
    f32x4 (&acc)[2][7])
{
    // ---- phase 1: [img(C), fltA(C) ready] ----
    #pragma unroll
    for (int j = 0; j < 4; ++j)                 // DMA fltB(C): 8w x 4 = 32 rounds
        GLOAD_LDS16(fsrcB + j * 8192 + C * 32, fdstB + j * 1024);
    if constexpr (C < 3) {                      // DMA img(C+1): 8w x <=5 rounds
        char* d = sdstI + ((C + 1) & 1) * IMG_BUF;
        #pragma unroll
        for (int k = 0; k < 5; ++k)
            if (gsite[k] >= 0)
                GLOAD_LDS16(imgT + gsite[k] + (C + 1) * 32, d + k * 1024);
    }
    compute_taps<0, 5>(aA, bB + (C & 1) * IMG_BUF, acc);
    __syncthreads();
    // ---- phase 2: [fltB(C) ready] ----
    if constexpr (C < 3) {
        #pragma unroll
        for (int j = 0; j < 5; ++j)             // DMA fltA(C+1): 8w x 5 = 40 rounds
            GLOAD_LDS16(fsrcA + j * 8192 + (C + 1) * 32, fdstA + j * 1024);
    }
    compute_taps<5, 9>(aB, bB + (C & 1) * IMG_BUF, acc);
    __syncthreads();
}

__global__ __launch_bounds__(512, 1) void conv_mfma(
    const unsigned short* __restrict__ imgT,
    const unsigned short* __restrict__ filtF,
    float* __restrict__ out)
{
    __shared__ char lds[LDS_BYTES];

    const int tid  = threadIdx.x;
    const int lane = tid & 63, w8 = tid >> 6;
    const int rp   = w8 >> 1, mh = w8 & 1;
    const int sub  = lane & 15, kg = lane >> 4;
    const int ysub = sub >> 3,  xl = sub & 7;

    // XCD swizzle (896 = 8*112), cot fastest -> 4 blocks share img tile in L2
    const int w    = (blockIdx.x & 7) * 112 + (blockIdx.x >> 3);
    const int cot  = w & 3;
    const int rest = w >> 2;
    const int strip = rest % 7;
    const int b     = rest / 7;
    const int co0   = cot * 64;
    const int ystart = (strip < 6) ? strip * 8 : (OH - 8);

    char* const pImg  = lds;
    char* const pFltA = lds + FLTA_OFF;
    char* const pFltB = lds + FLTB_OFF;
    const char* bB = pImg + kg * IMG_PLANE + (2 * rp + ysub) * IMG_ROWB + xl * 16;
    const char* aA = pFltA + kg * FLTA_PLANE + sub * 16 + mh * 512;
    const char* aB = pFltB + kg * FLTB_PLANE + sub * 16 + mh * 512;

    // filter stage src: per-lane base (plane = rp), t2-range split by mh
    const unsigned short* fsrc0 = filtF + (size_t)cot * 147456
                                + sub * 512 + kg * 128 + rp * 8;
    const unsigned short* fsrcA = fsrc0 + mh * 5 * 8192;          // t2 = mh*5 + j
    const unsigned short* fsrcB = fsrc0 + (10 + mh * 4) * 8192;   // t2 = 10 + mh*4 + j

    // stage dst bases (plane = rp, round offset folded in)
    char* sdstI = pImg  + rp * IMG_PLANE  + (mh * 320 + lane) * 16;  // + k*1024
    char* fdstA = pFltA + rp * FLTA_PLANE + (mh * 320 + lane) * 16;  // + j*1024
    char* fdstB = pFltB + rp * FLTB_PLANE + (mh * 256 + lane) * 16;  // + j*1024

    // img staging global offsets: wave (rp,mh) stages plane rp,
    // sites (mh*320 + k*64 + lane), k = 0..4; invalid sites -> -1
    int gsite[5];
    #pragma unroll
    for (int k = 0; k < 5; ++k) {
        const int site = mh * 320 + k * 64 + lane;
        const int rr = site / 56;
        const int xx = site - rr * 56;
        gsite[k] = (site < 560)
                 ? ((b * HH + ystart + rr) * WW + xx) * CIN + rp * 8
                 : -1;
    }

    f32x4 acc[2][7];
    #pragma unroll
    for (int mm = 0; mm < 2; ++mm)
        #pragma unroll
        for (int nf = 0; nf < 7; ++nf) acc[mm][nf] = (f32x4)0.0f;

    // prologue: stage img(0) + fltA(0)
    #pragma unroll
    for (int k = 0; k < 5; ++k)
        if (gsite[k] >= 0)
            GLOAD_LDS16(imgT + gsite[k], sdstI + k * 1024);
    #pragma unroll
    for (int j = 0; j < 5; ++j)
        GLOAD_LDS16(fsrcA + j * 8192, fdstA + j * 1024);
    __syncthreads();

    conv_iter<0>(imgT, fsrcA, fsrcB, sdstI, fdstA, fdstB, bB, aA, aB, gsite, acc);
    conv_iter<1>(imgT, fsrcA, fsrcB, sdstI, fdstA, fdstB, bB, aA, aB, gsite, acc);
    conv_iter<2>(imgT, fsrcA, fsrcB, sdstI, fdstA, fdstB, bB, aA, aB, gsite, acc);
    conv_iter<3>(imgT, fsrcA, fsrcB, sdstI, fdstA, fdstB, bB, aA, aB, gsite, acc);

    // epilogue: D col=lane&15 -> spatial, row=kg*4+j -> co; m = mh*2+mm
    const int y = ystart + 2 * rp + ysub;
    #pragma unroll
    for (int mm = 0; mm < 2; ++mm) {
        const int cob = co0 + (mh * 2 + mm) * 16 + kg * 4;
        #pragma unroll
        for (int nf = 0; nf < 7; ++nf) {
            const int x = nf * 8 + xl;
            if (x < OW) {
                float* o = out + ((size_t)(b * COUT + cob) * OH + y) * OW + x;
                #pragma unroll
                for (int j = 0; j < 4; ++j)
                    o[(size_t)j * OH * OW] = acc[mm][nf][j];
            }
        }
    }
}

// ---------------- fp32 fallback (ws too small) ------------------------------
#define COB  16
#define THF  6
#define CIBF 2
#define IRF  (THF + 2)
__global__ __launch_bounds__(256) void conv3x3_fp32(
    const float* __restrict__ img, const float* __restrict__ flt,
    float* __restrict__ out)
{
    __shared__ float si[CIBF][IRF][WW];
    __shared__ float sf[CIBF][COB][9];
    const int tid = threadIdx.x;
    const int tx  = tid & 63;
    const int tg  = tid >> 6;
    int bid = blockIdx.x;
    const int ytile = bid % (OH / THF);  bid /= (OH / THF);
    const int cob   = bid % (COUT / COB); bid /= (COUT / COB);
    const int b     = bid;
    const int y0  = ytile * THF;
    const int co0 = cob * COB;
    float acc[4][THF];
    #pragma unroll
    for (int c = 0; c < 4; ++c)
        #pragma unroll
        for (int y = 0; y < THF; ++y) acc[c][y] = 0.0f;
    for (int ci0 = 0; ci0 < CIN; ci0 += CIBF) {
        for (int i = tid; i < CIBF * IRF * (WW / 4); i += 256) {
            const int cil = i / (IRF * (WW / 4));
            int rem = i - cil * (IRF * (WW / 4));
            const int r = rem / (WW / 4);
            const int v = rem - r * (WW / 4);
            const float4* src = reinterpret_cast<const float4*>(
                img + (((size_t)b * CIN + (ci0 + cil)) * HH + (y0 + r)) * WW) + v;
            reinterpret_cast<float4*>(&si[cil][r][0])[v] = *src;
        }
        for (int i = tid; i < CIBF * COB * 9; i += 256) {
            const int cil = i / (COB * 9);
            int rem = i - cil * (COB * 9);
            const int col = rem / 9;
            const int e   = rem - col * 9;
            sf[cil][col][e] = flt[(((size_t)(co0 + col)) * CIN + (ci0 + cil)) * 9 + e];
        }
        __syncthreads();
        if (tx < OW) {
            #pragma unroll
            for (int cil = 0; cil < CIBF; ++cil) {
                float f[4][9];
                #pragma unroll
                for (int c = 0; c < 4; ++c)
                    #pragma unroll
                    for (int e = 0; e < 9; ++e) f[c][e] = sf[cil][tg * 4 + c][e];
                float a[IRF][3];
                #pragma unroll
                for (int r = 0; r < IRF; ++r) {
                    a[r][0] = si[cil][r][tx + 0];
                    a[r][1] = si[cil][r][tx + 1];
                    a[r][2] = si[cil][r][tx + 2];
                }
                #pragma unroll
                for (int y = 0; y < THF; ++y)
                    #pragma unroll
                    for (int dy = 0; dy < 3; ++dy)
                        #pragma unroll
                        for (int c = 0; c < 4; ++c)
                            acc[c][y] = fmaf(a[y + dy][0], f[c][dy * 3 + 0],
                                        fmaf(a[y + dy][1], f[c][dy * 3 + 1],
                                        fmaf(a[y + dy][2], f[c][dy * 3 + 2], acc[c][y])));
            }
        }
        __syncthreads();
    }
    if (tx < OW) {
        #pragma unroll
        for (int c = 0; c < 4; ++c) {
            const int co = co0 + tg * 4 + c;
            #pragma unroll
            for (int y = 0; y < THF; ++y)
                out[(((size_t)b * COUT + co) * OH + (y0 + y)) * OW + tx] = acc[c][y];
        }
    }
}

extern "C" void kernel_launch(void* const* d_in, const int* in_sizes, int n_in,
                              void* d_out, int out_size, void* d_ws, size_t ws_size,
                              hipStream_t stream) {
    const float* img = (const float*)d_in[0];
    const float* flt = (const float*)d_in[1];
    float* out = (float*)d_out;

    const size_t IMGT_BYTES = (size_t)BB * HH * WW * CIN * 2;
    const size_t FILT_BYTES = (size_t)18 * COUT * CIN * 2;
    if (ws_size < IMGT_BYTES + FILT_BYTES) {
        conv3x3_fp32<<<BB * (COUT / COB) * (OH / THF), 256, 0, stream>>>(img, flt, out);
        return;
    }
    unsigned short* imgT  = (unsigned short*)d_ws;
    unsigned short* filtF = (unsigned short*)((char*)d_ws + IMGT_BYTES);

    prep_img<<<BB * HH, 256, 0, stream>>>(img, imgT);
    prep_flt<<<(COUT * CIN) / 256, 256, 0, stream>>>(flt, filtF);
    conv_mfma<<<4 * 7 * BB, 512, 0, stream>>>(imgT, filtF, out);   // 896 blocks
}

// Round 10
// 114.198 us; speedup vs baseline: 2.2382x; 1.2936x over previous
//
#include <hip/hip_runtime.h>

// Convoluzione: VALID 3x3 cross-correlation, NCHW.
// img [32,128,56,56] f32, filtro [256,128,3,3] f32 -> out [32,256,54,54] f32
// R10: single-bf16 filters (halves MFMA work + A-reads + filter staging);
//      dx-major tap order: read B-frags for dy=0,2 only, derive dy=1 via
//      DPP row_ror:8 (lane^8 swaps the frag's row halves) + cndmask on the
//      idle VALU pipe. Phase-buffered DMA schedule retained from R8/R9.

#define BB   32
#define CIN  128
#define COUT 256
#define HH   56
#define WW   56
#define OH   54
#define OW   54

typedef short bf16x8 __attribute__((ext_vector_type(8)));
typedef float f32x4  __attribute__((ext_vector_type(4)));
typedef unsigned short u16x8 __attribute__((ext_vector_type(8)));

#define GLOAD_LDS16(g, l) __builtin_amdgcn_global_load_lds( \
    (const __attribute__((address_space(1))) unsigned int*)(g), \
    (__attribute__((address_space(3))) unsigned int*)(l), 16, 0, 0)

static __device__ __forceinline__ unsigned short f2bf(float f) {
    unsigned int u = __float_as_uint(f);
    u += 0x7FFFu + ((u >> 16) & 1u);
    return (unsigned short)(u >> 16);
}

// ---------------- prep 1: img f32 NCHW -> imgT bf16 [b][y][x][ci] ----------
__global__ __launch_bounds__(256) void prep_img(const float* __restrict__ img,
                                                unsigned short* __restrict__ imgT) {
    const int b = blockIdx.x / HH;
    const int y = blockIdx.x - b * HH;
    for (int i = threadIdx.x; i < 16 * WW; i += 256) {
        const int g = i / WW;
        const int x = i - g * WW;
        unsigned short pk[8];
        #pragma unroll
        for (int j = 0; j < 8; ++j)
            pk[j] = f2bf(img[((size_t)(b * CIN + g * 8 + j) * HH + y) * WW + x]);
        *(u16x8*)(imgT + ((size_t)(b * HH + y) * WW + x) * CIN + g * 8) = *(u16x8*)pk;
    }
}

// ---- prep 2: filtro f32 OIHW -> filtF[cot][t 9][sub][m][c][kg][e] bf16 ----
// co = cot*64 + m*16 + sub; ci = c*32 + kg*8 + e. Single bf16 (RNE).
__global__ __launch_bounds__(256) void prep_flt(const float* __restrict__ flt,
                                                unsigned short* __restrict__ filtF) {
    const int idx = blockIdx.x * 256 + threadIdx.x;   // 0..32767
    const int co = idx >> 7;
    const int ci = idx & 127;
    const int cot = co >> 6, col = co & 63;
    const int m = col >> 4, sub = col & 15;
    const int c = ci >> 5, kg = (ci >> 3) & 3, e = ci & 7;
    const size_t base = (size_t)cot * 73728 + sub * 512 + m * 128 + c * 32 + kg * 8 + e;
    #pragma unroll
    for (int t = 0; t < 9; ++t)
        filtF[base + t * 8192] = f2bf(flt[(size_t)(co * CIN + ci) * 9 + t]);
}

// ---------------- conv kernel ----------------------------------------------
// 512 thr / 8 waves, 1 block/CU. Tile: 64co x 8rows x 56cols.
// wave = (rp = w>>1 rowpair, mh = w&1 m-half); per wave 2m x 7nf, acc 56.
// LDS: img 2 x (4 kg-planes x 576 sites x 16B) = 73728
//      fltA region: slots {dx0,dx1}x{dy0,1,2} = 6 x [kg4][co64]x16 = 24576
//      fltB region: slots {dx2}x{dy}          = 3 x [kg4][co64]x16 = 12288
#define IMG_ROWB   896
#define IMG_PLANE  9216
#define IMG_BUF    36864
#define FA_OFF     73728
#define FB_OFF     98304          // FA_OFF + 24576
#define LDS_BYTES  110592         // FB_OFF + 12288

static __device__ __forceinline__ int dpp_ror8(int x) {
    return __builtin_amdgcn_update_dpp(0, x, 0x128, 0xF, 0xF, true); // row_ror:8
}
static __device__ __forceinline__ bf16x8 rot8(bf16x8 v) {
    union { bf16x8 h; int i[4]; } u, r;
    u.h = v;
    #pragma unroll
    for (int k = 0; k < 4; ++k) r.i[k] = dpp_ror8(u.i[k]);
    return r.h;
}
static __device__ __forceinline__ bf16x8 sel8(bool c0, bf16x8 a, bf16x8 b) {
    union { bf16x8 h; int i[4]; } ua, ub, o;
    ua.h = a; ub.h = b;
    #pragma unroll
    for (int k = 0; k < 4; ++k) o.i[k] = c0 ? ua.i[k] : ub.i[k];
    return o.h;
}

// one dx-group: read b0(dy0), b2(dy2); derive b1; 3 taps x 2m x 7nf MFMA.
// aBase is per-lane (incl kg*1024 + mh*512 + sub*16); slot s0 = region slot of dy0.
template<int DX, int S0>
static __device__ __forceinline__ void do_dx(const char* __restrict__ aBase,
                                             const char* __restrict__ bBc,
                                             const bool ysub0,
                                             f32x4 (&acc)[2][7])
{
    bf16x8 b0[7], b2[7];
    #pragma unroll
    for (int nf = 0; nf < 7; ++nf)
        b0[nf] = *(const bf16x8*)(bBc + (nf * 8 + DX) * 16);
    #pragma unroll
    for (int nf = 0; nf < 7; ++nf)
        b2[nf] = *(const bf16x8*)(bBc + 2 * IMG_ROWB + (nf * 8 + DX) * 16);

    // dy = 0
    {
        bf16x8 a0 = *(const bf16x8*)(aBase + (S0 + 0) * 4096);
        bf16x8 a1 = *(const bf16x8*)(aBase + (S0 + 0) * 4096 + 256);
        #pragma unroll
        for (int nf = 0; nf < 7; ++nf) {
            acc[0][nf] = __builtin_amdgcn_mfma_f32_16x16x32_bf16(a0, b0[nf], acc[0][nf], 0, 0, 0);
            acc[1][nf] = __builtin_amdgcn_mfma_f32_16x16x32_bf16(a1, b0[nf], acc[1][nf], 0, 0, 0);
        }
    }
    // dy = 1 (derived: lane^8 swaps ysub halves; ysub0 takes rot(b0), else rot(b2))
    {
        bf16x8 a0 = *(const bf16x8*)(aBase + (S0 + 1) * 4096);
        bf16x8 a1 = *(const bf16x8*)(aBase + (S0 + 1) * 4096 + 256);
        #pragma unroll
        for (int nf = 0; nf < 7; ++nf) {
            bf16x8 b1 = sel8(ysub0, rot8(b0[nf]), rot8(b2[nf]));
            acc[0][nf] = __builtin_amdgcn_mfma_f32_16x16x32_bf16(a0, b1, acc[0][nf], 0, 0, 0);
            acc[1][nf] = __builtin_amdgcn_mfma_f32_16x16x32_bf16(a1, b1, acc[1][nf], 0, 0, 0);
        }
    }
    // dy = 2
    {
        bf16x8 a0 = *(const bf16x8*)(aBase + (S0 + 2) * 4096);
        bf16x8 a1 = *(const bf16x8*)(aBase + (S0 + 2) * 4096 + 256);
        #pragma unroll
        for (int nf = 0; nf < 7; ++nf) {
            acc[0][nf] = __builtin_amdgcn_mfma_f32_16x16x32_bf16(a0, b2[nf], acc[0][nf], 0, 0, 0);
            acc[1][nf] = __builtin_amdgcn_mfma_f32_16x16x32_bf16(a1, b2[nf], acc[1][nf], 0, 0, 0);
        }
    }
}

// A-region slot -> tap: slots {0,1,2} = dx0,dy{0,1,2} -> t=3*dy; {3,4,5} = dx1 -> t=3*dy+1
static __device__ __forceinline__ constexpr int tapA(int s) {
    return (s < 3) ? 3 * s : 3 * (s - 3) + 1;
}

template<int C>
static __device__ __forceinline__ void conv_iter(
    const unsigned short* __restrict__ imgT,
    const unsigned short* __restrict__ fcot,   // filtF + cot*73728
    const int flane, const int hi, const int tid,
    char* __restrict__ pFA, char* __restrict__ pFB,
    char* __restrict__ sdstI,
    const char* __restrict__ bB, const char* __restrict__ aA, const char* __restrict__ aB,
    const int (&gsite)[5], const bool ysub0,
    f32x4 (&acc)[2][7])
{
    // ---- phase 1: [img(C), fltA(C) ready] ----
    {   // DMA fltB(C): slots {0,1} then slot 2 (taps 2,5,8)
        GLOAD_LDS16(fcot + flane + (hi ? 5 : 2) * 8192 + C * 32, pFB + tid * 16);
        if (tid < 256)
            GLOAD_LDS16(fcot + flane + 8 * 8192 + C * 32, pFB + 8192 + tid * 16);
    }
    if constexpr (C < 3) {                     // DMA img(C+1)
        char* d = sdstI + ((C + 1) & 1) * IMG_BUF;
        #pragma unroll
        for (int k = 0; k < 5; ++k)
            if (gsite[k] >= 0)
                GLOAD_LDS16(imgT + gsite[k] + (C + 1) * 32, d + k * 1024);
    }
    const char* bBc = bB + (C & 1) * IMG_BUF;
    do_dx<0, 0>(aA, bBc, ysub0, acc);
    do_dx<1, 3>(aA, bBc, ysub0, acc);
    __syncthreads();
    // ---- phase 2: [fltB(C) ready] ----
    if constexpr (C < 3) {                     // DMA fltA(C+1): 3 rounds, 2 slots each
        GLOAD_LDS16(fcot + flane + (hi ? tapA(1) : tapA(0)) * 8192 + (C + 1) * 32, pFA + 0 * 8192 + tid * 16);
        GLOAD_LDS16(fcot + flane + (hi ? tapA(3) : tapA(2)) * 8192 + (C + 1) * 32, pFA + 1 * 8192 + tid * 16);
        GLOAD_LDS16(fcot + flane + (hi ? tapA(5) : tapA(4)) * 8192 + (C + 1) * 32, pFA + 2 * 8192 + tid * 16);
    }
    do_dx<2, 0>(aB, bBc, ysub0, acc);
    __syncthreads();
}

__global__ __launch_bounds__(512, 1) void conv_mfma(
    const unsigned short* __restrict__ imgT,
    const unsigned short* __restrict__ filtF,
    float* __restrict__ out)
{
    __shared__ char lds[LDS_BYTES];

    const int tid  = threadIdx.x;
    const int lane = tid & 63, w8 = tid >> 6;
    const int rp   = w8 >> 1, mh = w8 & 1;
    const int sub  = lane & 15, kg = lane >> 4;
    const int ysub = sub >> 3,  xl = sub & 7;
    const bool ysub0 = (ysub == 0);
    const int hi = tid >> 8;                    // 0/1: staging slot parity

    // XCD swizzle (896 = 8*112), cot fastest -> 4 blocks share img tile in L2
    const int w    = (blockIdx.x & 7) * 112 + (blockIdx.x >> 3);
    const int cot  = w & 3;
    const int rest = w >> 2;
    const int strip = rest % 7;
    const int b     = rest / 7;
    const int co0   = cot * 64;
    const int ystart = (strip < 6) ? strip * 8 : (OH - 8);

    char* const pImg = lds;
    char* const pFA  = lds + FA_OFF;
    char* const pFB  = lds + FB_OFF;
    const char* bB = pImg + kg * IMG_PLANE + (2 * rp + ysub) * IMG_ROWB + xl * 16;
    const char* aA = pFA + kg * 1024 + mh * 512 + sub * 16;   // + slot*4096 + mm*256
    const char* aB = pFB + kg * 1024 + mh * 512 + sub * 16;

    const unsigned short* fcot = filtF + (size_t)cot * 73728;
    // staging roles: co = tid&63, kg_s = (tid>>6)&3
    const int flane = ((tid & 15) * 512) + (((tid >> 4) & 3) * 128) + (((tid >> 6) & 3) * 8);

    // img staging: wave (rp,mh) stages kg-plane rp, sites mh*320 + k*64 + lane
    char* sdstI = pImg + rp * IMG_PLANE + (mh * 320 + lane) * 16;
    int gsite[5];
    #pragma unroll
    for (int k = 0; k < 5; ++k) {
        const int site = mh * 320 + k * 64 + lane;
        const int rr = site / 56;
        const int xx = site - rr * 56;
        gsite[k] = (site < 560)
                 ? ((b * HH + ystart + rr) * WW + xx) * CIN + rp * 8
                 : -1;
    }

    f32x4 acc[2][7];
    #pragma unroll
    for (int mm = 0; mm < 2; ++mm)
        #pragma unroll
        for (int nf = 0; nf < 7; ++nf) acc[mm][nf] = (f32x4)0.0f;

    // prologue: stage img(0) + fltA(0)
    #pragma unroll
    for (int k = 0; k < 5; ++k)
        if (gsite[k] >= 0)
            GLOAD_LDS16(imgT + gsite[k], sdstI + k * 1024);
    GLOAD_LDS16(fcot + flane + (hi ? tapA(1) : tapA(0)) * 8192, pFA + 0 * 8192 + tid * 16);
    GLOAD_LDS16(fcot + flane + (hi ? tapA(3) : tapA(2)) * 8192, pFA + 1 * 8192 + tid * 16);
    GLOAD_LDS16(fcot + flane + (hi ? tapA(5) : tapA(4)) * 8192, pFA + 2 * 8192 + tid * 16);
    __syncthreads();

    conv_iter<0>(imgT, fcot, flane, hi, tid, pFA, pFB, sdstI, bB, aA, aB, gsite, ysub0, acc);
    conv_iter<1>(imgT, fcot, flane, hi, tid, pFA, pFB, sdstI, bB, aA, aB, gsite, ysub0, acc);
    conv_iter<2>(imgT, fcot, flane, hi, tid, pFA, pFB, sdstI, bB, aA, aB, gsite, ysub0, acc);
    conv_iter<3>(imgT, fcot, flane, hi, tid, pFA, pFB, sdstI, bB, aA, aB, gsite, ysub0, acc);

    // epilogue: D col=lane&15 -> spatial, row=kg*4+j -> co; m = mh*2+mm
    const int y = ystart + 2 * rp + ysub;
    #pragma unroll
    for (int mm = 0; mm < 2; ++mm) {
        const int cob = co0 + (mh * 2 + mm) * 16 + kg * 4;
        #pragma unroll
        for (int nf = 0; nf < 7; ++nf) {
            const int x = nf * 8 + xl;
            if (x < OW) {
                float* o = out + ((size_t)(b * COUT + cob) * OH + y) * OW + x;
                #pragma unroll
                for (int j = 0; j < 4; ++j)
                    o[(size_t)j * OH * OW] = acc[mm][nf][j];
            }
        }
    }
}

// ---------------- fp32 fallback (ws too small) ------------------------------
#define COB  16
#define THF  6
#define CIBF 2
#define IRF  (THF + 2)
__global__ __launch_bounds__(256) void conv3x3_fp32(
    const float* __restrict__ img, const float* __restrict__ flt,
    float* __restrict__ out)
{
    __shared__ float si[CIBF][IRF][WW];
    __shared__ float sf[CIBF][COB][9];
    const int tid = threadIdx.x;
    const int tx  = tid & 63;
    const int tg  = tid >> 6;
    int bid = blockIdx.x;
    const int ytile = bid % (OH / THF);  bid /= (OH / THF);
    const int cob   = bid % (COUT / COB); bid /= (COUT / COB);
    const int b     = bid;
    const int y0  = ytile * THF;
    const int co0 = cob * COB;
    float acc[4][THF];
    #pragma unroll
    for (int c = 0; c < 4; ++c)
        #pragma unroll
        for (int y = 0; y < THF; ++y) acc[c][y] = 0.0f;
    for (int ci0 = 0; ci0 < CIN; ci0 += CIBF) {
        for (int i = tid; i < CIBF * IRF * (WW / 4); i += 256) {
            const int cil = i / (IRF * (WW / 4));
            int rem = i - cil * (IRF * (WW / 4));
            const int r = rem / (WW / 4);
            const int v = rem - r * (WW / 4);
            const float4* src = reinterpret_cast<const float4*>(
                img + (((size_t)b * CIN + (ci0 + cil)) * HH + (y0 + r)) * WW) + v;
            reinterpret_cast<float4*>(&si[cil][r][0])[v] = *src;
        }
        for (int i = tid; i < CIBF * COB * 9; i += 256) {
            const int cil = i / (COB * 9);
            int rem = i - cil * (COB * 9);
            const int col = rem / 9;
            const int e   = rem - col * 9;
            sf[cil][col][e] = flt[(((size_t)(co0 + col)) * CIN + (ci0 + cil)) * 9 + e];
        }
        __syncthreads();
        if (tx < OW) {
            #pragma unroll
            for (int cil = 0; cil < CIBF; ++cil) {
                float f[4][9];
                #pragma unroll
                for (int c = 0; c < 4; ++c)
                    #pragma unroll
                    for (int e = 0; e < 9; ++e) f[c][e] = sf[cil][tg * 4 + c][e];
                float a[IRF][3];
                #pragma unroll
                for (int r = 0; r < IRF; ++r) {
                    a[r][0] = si[cil][r][tx + 0];
                    a[r][1] = si[cil][r][tx + 1];
                    a[r][2] = si[cil][r][tx + 2];
                }
                #pragma unroll
                for (int y = 0; y < THF; ++y)
                    #pragma unroll
                    for (int dy = 0; dy < 3; ++dy)
                        #pragma unroll
                        for (int c = 0; c < 4; ++c)
                            acc[c][y] = fmaf(a[y + dy][0], f[c][dy * 3 + 0],
                                        fmaf(a[y + dy][1], f[c][dy * 3 + 1],
                                        fmaf(a[y + dy][2], f[c][dy * 3 + 2], acc[c][y])));
            }
        }
        __syncthreads();
    }
    if (tx < OW) {
        #pragma unroll
        for (int c = 0; c < 4; ++c) {
            const int co = co0 + tg * 4 + c;
            #pragma unroll
            for (int y = 0; y < THF; ++y)
                out[(((size_t)b * COUT + co) * OH + (y0 + y)) * OW + tx] = acc[c][y];
        }
    }
}

extern "C" void kernel_launch(void* const* d_in, const int* in_sizes, int n_in,
                              void* d_out, int out_size, void* d_ws, size_t ws_size,
                              hipStream_t stream) {
    const float* img = (const float*)d_in[0];
    const float* flt = (const float*)d_in[1];
    float* out = (float*)d_out;

    const size_t IMGT_BYTES = (size_t)BB * HH * WW * CIN * 2;   // 25,690,112
    const size_t FILT_BYTES = (size_t)4 * 73728 * 2;            //     589,824
    if (ws_size < IMGT_BYTES + FILT_BYTES) {
        conv3x3_fp32<<<BB * (COUT / COB) * (OH / THF), 256, 0, stream>>>(img, flt, out);
        return;
    }
    unsigned short* imgT  = (unsigned short*)d_ws;
    unsigned short* filtF = (unsigned short*)((char*)d_ws + IMGT_BYTES);

    prep_img<<<BB * HH, 256, 0, stream>>>(img, imgT);
    prep_flt<<<(COUT * CIN) / 256, 256, 0, stream>>>(flt, filtF);
    conv_mfma<<<4 * 7 * BB, 512, 0, stream>>>(imgT, filtF, out);   // 896 blocks
}

// Round 11
// 112.357 us; speedup vs baseline: 2.2748x; 1.0164x over previous
//
#include <hip/hip_runtime.h>

// Convoluzione: VALID 3x3 cross-correlation, NCHW.
// img [32,128,56,56] f32, filtro [256,128,3,3] f32 -> out [32,256,54,54] f32
// R11: single-phase c-iters. img AND filters fully double-buffered (144KB LDS);
//      per iter: issue all staging for c+1 (waves 0-3: img planes, 4-7: filter
//      slots; 9 uniform loads/wave) -> 9-tap MFMA burst (setprio) -> one
//      vmcnt(0)+s_barrier. 3 barriers/block vs R10's 8 drain-0 barriers.
//      Keeps R10 arithmetic: single-bf16 filters, DPP-derived dy=1 taps.

#define BB   32
#define CIN  128
#define COUT 256
#define HH   56
#define WW   56
#define OH   54
#define OW   54

typedef short bf16x8 __attribute__((ext_vector_type(8)));
typedef float f32x4  __attribute__((ext_vector_type(4)));
typedef unsigned short u16x8 __attribute__((ext_vector_type(8)));

#define GLOAD_LDS16(g, l) __builtin_amdgcn_global_load_lds( \
    (const __attribute__((address_space(1))) unsigned int*)(g), \
    (__attribute__((address_space(3))) unsigned int*)(l), 16, 0, 0)

static __device__ __forceinline__ unsigned short f2bf(float f) {
    unsigned int u = __float_as_uint(f);
    u += 0x7FFFu + ((u >> 16) & 1u);
    return (unsigned short)(u >> 16);
}

// ---------------- prep 1: img f32 NCHW -> imgT bf16 [b][y][x][ci] ----------
__global__ __launch_bounds__(256) void prep_img(const float* __restrict__ img,
                                                unsigned short* __restrict__ imgT) {
    const int b = blockIdx.x / HH;
    const int y = blockIdx.x - b * HH;
    for (int i = threadIdx.x; i < 16 * WW; i += 256) {
        const int g = i / WW;
        const int x = i - g * WW;
        unsigned short pk[8];
        #pragma unroll
        for (int j = 0; j < 8; ++j)
            pk[j] = f2bf(img[((size_t)(b * CIN + g * 8 + j) * HH + y) * WW + x]);
        *(u16x8*)(imgT + ((size_t)(b * HH + y) * WW + x) * CIN + g * 8) = *(u16x8*)pk;
    }
}

// ---- prep 2: filtro f32 OIHW -> filtF[cot][t 9][sub][m][c][kg][e] bf16 ----
// co = cot*64 + m*16 + sub; ci = c*32 + kg*8 + e. Single bf16 (RNE).
__global__ __launch_bounds__(256) void prep_flt(const float* __restrict__ flt,
                                                unsigned short* __restrict__ filtF) {
    const int idx = blockIdx.x * 256 + threadIdx.x;   // 0..32767
    const int co = idx >> 7;
    const int ci = idx & 127;
    const int cot = co >> 6, col = co & 63;
    const int m = col >> 4, sub = col & 15;
    const int c = ci >> 5, kg = (ci >> 3) & 3, e = ci & 7;
    const size_t base = (size_t)cot * 73728 + sub * 512 + m * 128 + c * 32 + kg * 8 + e;
    #pragma unroll
    for (int t = 0; t < 9; ++t)
        filtF[base + t * 8192] = f2bf(flt[(size_t)(co * CIN + ci) * 9 + t]);
}

// ---------------- conv kernel ----------------------------------------------
// 512 thr / 8 waves, 1 block/CU. Tile: 64co x 8rows x 56cols.
// wave = (rp = w>>1 rowpair, mh = w&1 m-half).
// LDS: img  2 bufs x (4 kg-planes x 576 sites x 16B) = 73728
//      flt  2 bufs x (9 t-slots x 4 kg x 64 co x 16B) = 73728
#define IMG_ROWB   896
#define IMG_PLANE  9216          // 576 sites (560 real rows*cols + 16 pad)
#define BUF_SZ     36864
#define FLT_OFF    73728
#define LDS_BYTES  147456

static __device__ __forceinline__ int dpp_ror8(int x) {
    return __builtin_amdgcn_update_dpp(0, x, 0x128, 0xF, 0xF, true); // row_ror:8
}
static __device__ __forceinline__ bf16x8 rot8(bf16x8 v) {
    union { bf16x8 h; int i[4]; } u, r;
    u.h = v;
    #pragma unroll
    for (int k = 0; k < 4; ++k) r.i[k] = dpp_ror8(u.i[k]);
    return r.h;
}
static __device__ __forceinline__ bf16x8 sel8(bool c0, bf16x8 a, bf16x8 b) {
    union { bf16x8 h; int i[4]; } ua, ub, o;
    ua.h = a; ub.h = b;
    #pragma unroll
    for (int k = 0; k < 4; ++k) o.i[k] = c0 ? ua.i[k] : ub.i[k];
    return o.h;
}

// one dx-group: taps (dy,dx) for dy=0,1,2 at slot = dy*3+DX.
// b0 = img row +0, b2 = img row +2; dy1 B derived via lane^8 row swap.
template<int DX>
static __device__ __forceinline__ void do_dx(const char* __restrict__ aB,
                                             const char* __restrict__ bBc,
                                             const bool ysub0,
                                             f32x4 (&acc)[2][7])
{
    bf16x8 b0[7], b2[7];
    #pragma unroll
    for (int nf = 0; nf < 7; ++nf)
        b0[nf] = *(const bf16x8*)(bBc + (nf * 8 + DX) * 16);
    #pragma unroll
    for (int nf = 0; nf < 7; ++nf)
        b2[nf] = *(const bf16x8*)(bBc + 2 * IMG_ROWB + (nf * 8 + DX) * 16);

    {   // dy = 0, slot DX
        bf16x8 a0 = *(const bf16x8*)(aB + (DX + 0) * 4096);
        bf16x8 a1 = *(const bf16x8*)(aB + (DX + 0) * 4096 + 256);
        #pragma unroll
        for (int nf = 0; nf < 7; ++nf) {
            acc[0][nf] = __builtin_amdgcn_mfma_f32_16x16x32_bf16(a0, b0[nf], acc[0][nf], 0, 0, 0);
            acc[1][nf] = __builtin_amdgcn_mfma_f32_16x16x32_bf16(a1, b0[nf], acc[1][nf], 0, 0, 0);
        }
    }
    {   // dy = 1, slot DX+3 (derived B)
        bf16x8 a0 = *(const bf16x8*)(aB + (DX + 3) * 4096);
        bf16x8 a1 = *(const bf16x8*)(aB + (DX + 3) * 4096 + 256);
        #pragma unroll
        for (int nf = 0; nf < 7; ++nf) {
            bf16x8 b1 = sel8(ysub0, rot8(b0[nf]), rot8(b2[nf]));
            acc[0][nf] = __builtin_amdgcn_mfma_f32_16x16x32_bf16(a0, b1, acc[0][nf], 0, 0, 0);
            acc[1][nf] = __builtin_amdgcn_mfma_f32_16x16x32_bf16(a1, b1, acc[1][nf], 0, 0, 0);
        }
    }
    {   // dy = 2, slot DX+6
        bf16x8 a0 = *(const bf16x8*)(aB + (DX + 6) * 4096);
        bf16x8 a1 = *(const bf16x8*)(aB + (DX + 6) * 4096 + 256);
        #pragma unroll
        for (int nf = 0; nf < 7; ++nf) {
            acc[0][nf] = __builtin_amdgcn_mfma_f32_16x16x32_bf16(a0, b2[nf], acc[0][nf], 0, 0, 0);
            acc[1][nf] = __builtin_amdgcn_mfma_f32_16x16x32_bf16(a1, b2[nf], acc[1][nf], 0, 0, 0);
        }
    }
}

// stage all 9 of this wave's loads for c-iter CN into buffer CN&1
template<int CN>
static __device__ __forceinline__ void stage_all(
    const unsigned short* __restrict__ gsrc,
    char* __restrict__ dbase,            // role dst (buf 0) incl lane*16
    const int (&offs)[9])
{
    char* d = dbase + (CN & 1) * BUF_SZ;
    #pragma unroll
    for (int r = 0; r < 9; ++r)
        GLOAD_LDS16(gsrc + offs[r] + CN * 32, d + r * 1024);
}

template<int C>
static __device__ __forceinline__ void conv_iter(
    const unsigned short* __restrict__ gsrc,
    char* __restrict__ dbase, const int (&offs)[9],
    const char* __restrict__ aBase, const char* __restrict__ bBbase,
    const bool ysub0, f32x4 (&acc)[2][7])
{
    if constexpr (C < 3) stage_all<C + 1>(gsrc, dbase, offs);
    const char* aB  = aBase  + (C & 1) * BUF_SZ;
    const char* bBc = bBbase + (C & 1) * BUF_SZ;
    __builtin_amdgcn_s_setprio(1);
    do_dx<0>(aB, bBc, ysub0, acc);
    do_dx<1>(aB, bBc, ysub0, acc);
    do_dx<2>(aB, bBc, ysub0, acc);
    __builtin_amdgcn_s_setprio(0);
    if constexpr (C < 3) {
        asm volatile("s_waitcnt vmcnt(0)" ::: "memory");
        __builtin_amdgcn_s_barrier();
        __builtin_amdgcn_sched_barrier(0);
    }
}

__global__ __launch_bounds__(512, 1) void conv_mfma(
    const unsigned short* __restrict__ imgT,
    const unsigned short* __restrict__ filtF,
    float* __restrict__ out)
{
    __shared__ char lds[LDS_BYTES];

    const int tid  = threadIdx.x;
    const int lane = tid & 63, w8 = tid >> 6;
    const int rp   = w8 >> 1, mh = w8 & 1;
    const int sub  = lane & 15, kg = lane >> 4;
    const int ysub = sub >> 3,  xl = sub & 7;
    const bool ysub0 = (ysub == 0);

    // XCD swizzle (896 = 8*112), cot fastest -> 4 blocks share img tile in L2
    const int w    = (blockIdx.x & 7) * 112 + (blockIdx.x >> 3);
    const int cot  = w & 3;
    const int rest = w >> 2;
    const int strip = rest % 7;
    const int b     = rest / 7;
    const int co0   = cot * 64;
    const int ystart = (strip < 6) ? strip * 8 : (OH - 8);

    char* const pImg = lds;
    char* const pFlt = lds + FLT_OFF;
    const char* bBbase = pImg + kg * IMG_PLANE + (2 * rp + ysub) * IMG_ROWB + xl * 16;
    const char* aBase  = pFlt + kg * 1024 + mh * 512 + sub * 16;
    const unsigned short* fcot = filtF + (size_t)cot * 73728;

    // ---- staging role: waves 0-3 stage img kg-plane w8; waves 4-7 stage
    //      filter linear sites v*576 + r*64 + lane (t = q>>2, kg = q&3, q=v*9+r)
    const unsigned short* gsrc;
    char* dbase;
    int offs[9];
    if (w8 < 4) {
        gsrc  = imgT;
        dbase = pImg + w8 * IMG_PLANE + lane * 16;
        #pragma unroll
        for (int r = 0; r < 9; ++r) {
            const int site = r * 64 + lane;
            const int rr = site / 56;
            const int xx = site - rr * 56;
            const int off = ((b * HH + ystart + rr) * WW + xx) * CIN + w8 * 8;
            offs[r] = (site < 560) ? off : offs[0];   // pad sites: clamp (r=0 always valid)
        }
    } else {
        const int v = w8 - 4;
        gsrc  = fcot;
        dbase = pFlt + v * 9216 + lane * 16;
        const int flane = (lane & 15) * 512 + (lane >> 4) * 128;
        #pragma unroll
        for (int r = 0; r < 9; ++r) {
            const int q = v * 9 + r;
            offs[r] = (q >> 2) * 8192 + (q & 3) * 8 + flane;
        }
    }

    f32x4 acc[2][7];
    #pragma unroll
    for (int mm = 0; mm < 2; ++mm)
        #pragma unroll
        for (int nf = 0; nf < 7; ++nf) acc[mm][nf] = (f32x4)0.0f;

    // prologue: stage iter 0 into buf 0
    stage_all<0>(gsrc, dbase, offs);
    asm volatile("s_waitcnt vmcnt(0)" ::: "memory");
    __builtin_amdgcn_s_barrier();
    __builtin_amdgcn_sched_barrier(0);

    conv_iter<0>(gsrc, dbase, offs, aBase, bBbase, ysub0, acc);
    conv_iter<1>(gsrc, dbase, offs, aBase, bBbase, ysub0, acc);
    conv_iter<2>(gsrc, dbase, offs, aBase, bBbase, ysub0, acc);
    conv_iter<3>(gsrc, dbase, offs, aBase, bBbase, ysub0, acc);

    // epilogue: D col=lane&15 -> spatial, row=kg*4+j -> co; m = mh*2+mm
    const int y = ystart + 2 * rp + ysub;
    #pragma unroll
    for (int mm = 0; mm < 2; ++mm) {
        const int cob = co0 + (mh * 2 + mm) * 16 + kg * 4;
        #pragma unroll
        for (int nf = 0; nf < 7; ++nf) {
            const int x = nf * 8 + xl;
            if (x < OW) {
                float* o = out + ((size_t)(b * COUT + cob) * OH + y) * OW + x;
                #pragma unroll
                for (int j = 0; j < 4; ++j)
                    o[(size_t)j * OH * OW] = acc[mm][nf][j];
            }
        }
    }
}

// ---------------- fp32 fallback (ws too small) ------------------------------
#define COB  16
#define THF  6
#define CIBF 2
#define IRF  (THF + 2)
__global__ __launch_bounds__(256) void conv3x3_fp32(
    const float* __restrict__ img, const float* __restrict__ flt,
    float* __restrict__ out)
{
    __shared__ float si[CIBF][IRF][WW];
    __shared__ float sf[CIBF][COB][9];
    const int tid = threadIdx.x;
    const int tx  = tid & 63;
    const int tg  = tid >> 6;
    int bid = blockIdx.x;
    const int ytile = bid % (OH / THF);  bid /= (OH / THF);
    const int cob   = bid % (COUT / COB); bid /= (COUT / COB);
    const int b     = bid;
    const int y0  = ytile * THF;
    const int co0 = cob * COB;
    float acc[4][THF];
    #pragma unroll
    for (int c = 0; c < 4; ++c)
        #pragma unroll
        for (int y = 0; y < THF; ++y) acc[c][y] = 0.0f;
    for (int ci0 = 0; ci0 < CIN; ci0 += CIBF) {
        for (int i = tid; i < CIBF * IRF * (WW / 4); i += 256) {
            const int cil = i / (IRF * (WW / 4));
            int rem = i - cil * (IRF * (WW / 4));
            const int r = rem / (WW / 4);
            const int v = rem - r * (WW / 4);
            const float4* src = reinterpret_cast<const float4*>(
                img + (((size_t)b * CIN + (ci0 + cil)) * HH + (y0 + r)) * WW) + v;
            reinterpret_cast<float4*>(&si[cil][r][0])[v] = *src;
        }
        for (int i = tid; i < CIBF * COB * 9; i += 256) {
            const int cil = i / (COB * 9);
            int rem = i - cil * (COB * 9);
            const int col = rem / 9;
            const int e   = rem - col * 9;
            sf[cil][col][e] = flt[(((size_t)(co0 + col)) * CIN + (ci0 + cil)) * 9 + e];
        }
        __syncthreads();
        if (tx < OW) {
            #pragma unroll
            for (int cil = 0; cil < CIBF; ++cil) {
                float f[4][9];
                #pragma unroll
                for (int c = 0; c < 4; ++c)
                    #pragma unroll
                    for (int e = 0; e < 9; ++e) f[c][e] = sf[cil][tg * 4 + c][e];
                float a[IRF][3];
                #pragma unroll
                for (int r = 0; r < IRF; ++r) {
                    a[r][0] = si[cil][r][tx + 0];
                    a[r][1] = si[cil][r][tx + 1];
                    a[r][2] = si[cil][r][tx + 2];
                }
                #pragma unroll
                for (int y = 0; y < THF; ++y)
                    #pragma unroll
                    for (int dy = 0; dy < 3; ++dy)
                        #pragma unroll
                        for (int c = 0; c < 4; ++c)
                            acc[c][y] = fmaf(a[y + dy][0], f[c][dy * 3 + 0],
                                        fmaf(a[y + dy][1], f[c][dy * 3 + 1],
                                        fmaf(a[y + dy][2], f[c][dy * 3 + 2], acc[c][y])));
            }
        }
        __syncthreads();
    }
    if (tx < OW) {
        #pragma unroll
        for (int c = 0; c < 4; ++c) {
            const int co = co0 + tg * 4 + c;
            #pragma unroll
            for (int y = 0; y < THF; ++y)
                out[(((size_t)b * COUT + co) * OH + (y0 + y)) * OW + tx] = acc[c][y];
        }
    }
}

extern "C" void kernel_launch(void* const* d_in, const int* in_sizes, int n_in,
                              void* d_out, int out_size, void* d_ws, size_t ws_size,
                              hipStream_t stream) {
    const float* img = (const float*)d_in[0];
    const float* flt = (const float*)d_in[1];
    float* out = (float*)d_out;

    const size_t IMGT_BYTES = (size_t)BB * HH * WW * CIN * 2;   // 25,690,112
    const size_t FILT_BYTES = (size_t)4 * 73728 * 2;            //     589,824
    if (ws_size < IMGT_BYTES + FILT_BYTES) {
        conv3x3_fp32<<<BB * (COUT / COB) * (OH / THF), 256, 0, stream>>>(img, flt, out);
        return;
    }
    unsigned short* imgT  = (unsigned short*)d_ws;
    unsigned short* filtF = (unsigned short*)((char*)d_ws + IMGT_BYTES);

    prep_img<<<BB * HH, 256, 0, stream>>>(img, imgT);
    prep_flt<<<(COUT * CIN) / 256, 256, 0, stream>>>(flt, filtF);
    conv_mfma<<<4 * 7 * BB, 512, 0, stream>>>(imgT, filtF, out);   // 896 blocks
}

// Round 12
// 94.569 us; speedup vs baseline: 2.7027x; 1.1881x over previous
//
#include <hip/hip_runtime.h>

// Convoluzione: VALID 3x3 cross-correlation, NCHW.
// img [32,128,56,56] f32, filtro [256,128,3,3] f32 -> out [32,256,54,54] f32
// R12: raise FLOP per LDS-read past the pipe balance point (402B/MFMA < 412):
//      tile 128co x 8r x 56c, wave = (co-half ch, rowpair rp), cf=4 x xo=7
//      (each B-read feeds 4 MFMAs, each A-read 7). No DPP derive. Filters in
//      two tap-regions (t0-4 / t5-8) each staged one barrier before use; img
//      double-buffered. 512 thr / 8 waves, 1 block/CU, 142KB LDS.

#define BB   32
#define CIN  128
#define COUT 256
#define HH   56
#define WW   56
#define OH   54
#define OW   54

typedef short bf16x8 __attribute__((ext_vector_type(8)));
typedef float f32x4  __attribute__((ext_vector_type(4)));
typedef unsigned short u16x8 __attribute__((ext_vector_type(8)));

#define GLOAD_LDS16(g, l) __builtin_amdgcn_global_load_lds( \
    (const __attribute__((address_space(1))) unsigned int*)(g), \
    (__attribute__((address_space(3))) unsigned int*)(l), 16, 0, 0)

static __device__ __forceinline__ unsigned short f2bf(float f) {
    unsigned int u = __float_as_uint(f);
    u += 0x7FFFu + ((u >> 16) & 1u);
    return (unsigned short)(u >> 16);
}

// ---------------- prep 1: img f32 NCHW -> imgT bf16 [b][y][x][ci] ----------
__global__ __launch_bounds__(256) void prep_img(const float* __restrict__ img,
                                                unsigned short* __restrict__ imgT) {
    const int b = blockIdx.x / HH;
    const int y = blockIdx.x - b * HH;
    for (int i = threadIdx.x; i < 16 * WW; i += 256) {
        const int g = i / WW;
        const int x = i - g * WW;
        unsigned short pk[8];
        #pragma unroll
        for (int j = 0; j < 8; ++j)
            pk[j] = f2bf(img[((size_t)(b * CIN + g * 8 + j) * HH + y) * WW + x]);
        *(u16x8*)(imgT + ((size_t)(b * HH + y) * WW + x) * CIN + g * 8) = *(u16x8*)pk;
    }
}

// ---- prep 2: filtro f32 OIHW -> filtG[cot2][c4][t9][kg4][col128][e8] bf16 --
// co = cot*128 + col; ci = c*32 + kg*8 + e. Single bf16 (RNE).
// Per (cot,c): 36864 elems; taps 0-4 = first 20480 (A-region), 5-8 next 16384 (B).
__global__ __launch_bounds__(256) void prep_flt(const float* __restrict__ flt,
                                                unsigned short* __restrict__ filtG) {
    const int idx = blockIdx.x * 256 + threadIdx.x;   // 0..32767
    const int co = idx >> 7;
    const int ci = idx & 127;
    const int cot = co >> 7, col = co & 127;
    const int c = ci >> 5, kg = (ci >> 3) & 3, e = ci & 7;
    const size_t base = (size_t)(cot * 4 + c) * 36864 + kg * 1024 + col * 8 + e;
    #pragma unroll
    for (int t = 0; t < 9; ++t)
        filtG[base + t * 4096] = f2bf(flt[(size_t)(co * CIN + ci) * 9 + t]);
}

// ---------------- conv kernel ----------------------------------------------
// 512 thr / 8 waves, 1 block/CU. Tile: 128co x 8rows x 56cols.
// wave = (ch = w>>2 co-half, rp = w&3 rowpair). Per wave: cf4 x xo7, acc 112.
// LDS: img 2 bufs x [kg4][row10][col56]x16B = 71680
//      fltA (taps0-4) [slot5][kg4][col128]x16B = 40960  @71680
//      fltB (taps5-8) [slot4][kg4][col128]x16B = 32768  @112640   tot 145408
#define IMG_ROWB  896            // 56*16
#define IMG_PLANE 8960           // 10 rows
#define IMG_BUF   35840          // 4 planes
#define FLTA_OFF  71680
#define FLTB_OFF  112640
#define LDS_BYTES 145408

// compute taps [T0, T0+NT): A from aR (+ slot*8192 + cf*256), B from bBc
template<int T0, int NT>
static __device__ __forceinline__ void compute_taps(const char* __restrict__ aR,
                                                    const char* __restrict__ bBc,
                                                    f32x4 (&acc)[4][7]) {
    #pragma unroll
    for (int tt = 0; tt < NT; ++tt) {
        const int t = T0 + tt;
        const int dy = t / 3, dx = t % 3;
        bf16x8 A[4];
        #pragma unroll
        for (int cf = 0; cf < 4; ++cf)
            A[cf] = *(const bf16x8*)(aR + tt * 8192 + cf * 256);
        #pragma unroll
        for (int xo = 0; xo < 7; ++xo) {
            bf16x8 bv = *(const bf16x8*)(bBc + dy * IMG_ROWB + (xo * 8 + dx) * 16);
            #pragma unroll
            for (int cf = 0; cf < 4; ++cf)
                acc[cf][xo] = __builtin_amdgcn_mfma_f32_16x16x32_bf16(A[cf], bv, acc[cf][xo], 0, 0, 0);
        }
    }
}

__global__ __launch_bounds__(512, 1) void conv_mfma(
    const unsigned short* __restrict__ imgT,
    const unsigned short* __restrict__ filtG,
    float* __restrict__ out)
{
    __shared__ char lds[LDS_BYTES];

    const int tid  = threadIdx.x;
    const int lane = tid & 63, w8 = tid >> 6;
    const int ch   = w8 >> 2, rp = w8 & 3;
    const int sub  = lane & 15, kg = lane >> 4;
    const int sr   = sub >> 3,  sc = sub & 7;

    // XCD swizzle (448 = 8*56), cot fastest -> 2 blocks share img tile in L2
    const int w    = (blockIdx.x & 7) * 56 + (blockIdx.x >> 3);
    const int cot  = w & 1;
    const int rest = w >> 1;
    const int strip = rest % 7;
    const int b     = rest / 7;
    const int co0   = cot * 128;
    const int ystart = (strip < 6) ? strip * 8 : (OH - 8);

    char* const pImg = lds;
    char* const pFA  = lds + FLTA_OFF;
    char* const pFB  = lds + FLTB_OFF;
    const char* bB = pImg + kg * IMG_PLANE + (rp * 2 + sr) * IMG_ROWB + sc * 16;
    const char* aA = pFA + kg * 2048 + (ch * 64 + sub) * 16;
    const char* aB = pFB + kg * 2048 + (ch * 64 + sub) * 16;

    // filter staging: linear sites (k*512 + tid) x 16B from per-(cot,c) block
    const unsigned short* fsrc = filtG + (size_t)cot * 147456;   // + c*36864 elems

    // img staging: 256-thread half-groups; hs = plane parity, 560 sites/plane
    const int hs = tid >> 8, t8 = tid & 255;
    int goffI[3];
    #pragma unroll
    for (int k = 0; k < 3; ++k) {
        const int s = k * 256 + t8;
        const int r = s / 56;
        const int x = s - r * 56;
        goffI[k] = ((b * HH + ystart + r) * WW + x) * CIN + hs * 8;   // s<560 guard at use
    }
    const bool act2 = (t8 < 48);   // site k=2 valid (560 = 2*256 + 48)

    #define STAGE_FA(cn) do { \
        _Pragma("unroll") \
        for (int k = 0; k < 5; ++k) \
            GLOAD_LDS16(fsrc + (cn) * 36864 + (k * 512 + tid) * 8, \
                        pFA + (k * 512 + tid) * 16); \
    } while (0)
    #define STAGE_FB(cn) do { \
        _Pragma("unroll") \
        for (int k = 0; k < 4; ++k) \
            GLOAD_LDS16(fsrc + (cn) * 36864 + 20480 + (k * 512 + tid) * 8, \
                        pFB + (k * 512 + tid) * 16); \
    } while (0)
    // planes 0-1 (ci c*32 + hs*8) / planes 2-3 (ci c*32 + 16 + hs*8)
    #define STAGE_I01(cn) do { \
        char* d_ = pImg + ((cn) & 1) * IMG_BUF + hs * IMG_PLANE; \
        _Pragma("unroll") \
        for (int k = 0; k < 3; ++k) \
            if (k < 2 || act2) \
                GLOAD_LDS16(imgT + goffI[k] + (cn) * 32, d_ + (k * 256 + t8) * 16); \
    } while (0)
    #define STAGE_I23(cn) do { \
        char* d_ = pImg + ((cn) & 1) * IMG_BUF + (2 + hs) * IMG_PLANE; \
        _Pragma("unroll") \
        for (int k = 0; k < 3; ++k) \
            if (k < 2 || act2) \
                GLOAD_LDS16(imgT + goffI[k] + (cn) * 32 + 16, d_ + (k * 256 + t8) * 16); \
    } while (0)
    #define PHASE_SYNC() do { \
        asm volatile("s_waitcnt vmcnt(0) lgkmcnt(0)" ::: "memory"); \
        __builtin_amdgcn_s_barrier(); \
        __builtin_amdgcn_sched_barrier(0); \
    } while (0)

    f32x4 acc[4][7];
    #pragma unroll
    for (int cf = 0; cf < 4; ++cf)
        #pragma unroll
        for (int xo = 0; xo < 7; ++xo) acc[cf][xo] = (f32x4)0.0f;

    // prologue: fltA(0) + img(0) all planes
    STAGE_FA(0);
    STAGE_I01(0);
    STAGE_I23(0);
    PHASE_SYNC();

    #define CONV_ITER(C) do { \
        /* phase A: taps 0-4; stage fltB(C) + img-planes01(C+1) */ \
        STAGE_FB(C); \
        if ((C) < 3) STAGE_I01((C) + 1); \
        { const char* bBc = bB + ((C) & 1) * IMG_BUF; \
          __builtin_amdgcn_s_setprio(1); \
          compute_taps<0, 5>(aA, bBc, acc); \
          __builtin_amdgcn_s_setprio(0); } \
        PHASE_SYNC(); \
        /* phase B: taps 5-8; stage fltA(C+1) + img-planes23(C+1) */ \
        if ((C) < 3) { STAGE_FA((C) + 1); STAGE_I23((C) + 1); } \
        { const char* bBc = bB + ((C) & 1) * IMG_BUF; \
          __builtin_amdgcn_s_setprio(1); \
          compute_taps<5, 4>(aB, bBc, acc); \
          __builtin_amdgcn_s_setprio(0); } \
        if ((C) < 3) PHASE_SYNC(); \
    } while (0)

    CONV_ITER(0);
    CONV_ITER(1);
    CONV_ITER(2);
    CONV_ITER(3);

    // epilogue: D col=lane&15 -> site (sr,sc), row=kg*4+j -> co
    const int y = ystart + rp * 2 + sr;
    #pragma unroll
    for (int cf = 0; cf < 4; ++cf) {
        const int cob = co0 + ch * 64 + cf * 16 + kg * 4;
        #pragma unroll
        for (int xo = 0; xo < 7; ++xo) {
            const int x = xo * 8 + sc;
            if (x < OW) {
                float* o = out + ((size_t)(b * COUT + cob) * OH + y) * OW + x;
                #pragma unroll
                for (int j = 0; j < 4; ++j)
                    o[(size_t)j * OH * OW] = acc[cf][xo][j];
            }
        }
    }
}

// ---------------- fp32 fallback (ws too small) ------------------------------
#define COB  16
#define THF  6
#define CIBF 2
#define IRF  (THF + 2)
__global__ __launch_bounds__(256) void conv3x3_fp32(
    const float* __restrict__ img, const float* __restrict__ flt,
    float* __restrict__ out)
{
    __shared__ float si[CIBF][IRF][WW];
    __shared__ float sf[CIBF][COB][9];
    const int tid = threadIdx.x;
    const int tx  = tid & 63;
    const int tg  = tid >> 6;
    int bid = blockIdx.x;
    const int ytile = bid % (OH / THF);  bid /= (OH / THF);
    const int cob   = bid % (COUT / COB); bid /= (COUT / COB);
    const int b     = bid;
    const int y0  = ytile * THF;
    const int co0 = cob * COB;
    float acc[4][THF];
    #pragma unroll
    for (int c = 0; c < 4; ++c)
        #pragma unroll
        for (int y = 0; y < THF; ++y) acc[c][y] = 0.0f;
    for (int ci0 = 0; ci0 < CIN; ci0 += CIBF) {
        for (int i = tid; i < CIBF * IRF * (WW / 4); i += 256) {
            const int cil = i / (IRF * (WW / 4));
            int rem = i - cil * (IRF * (WW / 4));
            const int r = rem / (WW / 4);
            const int v = rem - r * (WW / 4);
            const float4* src = reinterpret_cast<const float4*>(
                img + (((size_t)b * CIN + (ci0 + cil)) * HH + (y0 + r)) * WW) + v;
            reinterpret_cast<float4*>(&si[cil][r][0])[v] = *src;
        }
        for (int i = tid; i < CIBF * COB * 9; i += 256) {
            const int cil = i / (COB * 9);
            int rem = i - cil * (COB * 9);
            const int col = rem / 9;
            const int e   = rem - col * 9;
            sf[cil][col][e] = flt[(((size_t)(co0 + col)) * CIN + (ci0 + cil)) * 9 + e];
        }
        __syncthreads();
        if (tx < OW) {
            #pragma unroll
            for (int cil = 0; cil < CIBF; ++cil) {
                float f[4][9];
                #pragma unroll
                for (int c = 0; c < 4; ++c)
                    #pragma unroll
                    for (int e = 0; e < 9; ++e) f[c][e] = sf[cil][tg * 4 + c][e];
                float a[IRF][3];
                #pragma unroll
                for (int r = 0; r < IRF; ++r) {
                    a[r][0] = si[cil][r][tx + 0];
                    a[r][1] = si[cil][r][tx + 1];
                    a[r][2] = si[cil][r][tx + 2];
                }
                #pragma unroll
                for (int y = 0; y < THF; ++y)
                    #pragma unroll
                    for (int dy = 0; dy < 3; ++dy)
                        #pragma unroll
                        for (int c = 0; c < 4; ++c)
                            acc[c][y] = fmaf(a[y + dy][0], f[c][dy * 3 + 0],
                                        fmaf(a[y + dy][1], f[c][dy * 3 + 1],
                                        fmaf(a[y + dy][2], f[c][dy * 3 + 2], acc[c][y])));
            }
        }
        __syncthreads();
    }
    if (tx < OW) {
        #pragma unroll
        for (int c = 0; c < 4; ++c) {
            const int co = co0 + tg * 4 + c;
            #pragma unroll
            for (int y = 0; y < THF; ++y)
                out[(((size_t)b * COUT + co) * OH + (y0 + y)) * OW + tx] = acc[c][y];
        }
    }
}

extern "C" void kernel_launch(void* const* d_in, const int* in_sizes, int n_in,
                              void* d_out, int out_size, void* d_ws, size_t ws_size,
                              hipStream_t stream) {
    const float* img = (const float*)d_in[0];
    const float* flt = (const float*)d_in[1];
    float* out = (float*)d_out;

    const size_t IMGT_BYTES = (size_t)BB * HH * WW * CIN * 2;   // 25,690,112
    const size_t FILT_BYTES = (size_t)2 * 4 * 36864 * 2;        //     589,824
    if (ws_size < IMGT_BYTES + FILT_BYTES) {
        conv3x3_fp32<<<BB * (COUT / COB) * (OH / THF), 256, 0, stream>>>(img, flt, out);
        return;
    }
    unsigned short* imgT  = (unsigned short*)d_ws;
    unsigned short* filtG = (unsigned short*)((char*)d_ws + IMGT_BYTES);

    prep_img<<<BB * HH, 256, 0, stream>>>(img, imgT);
    prep_flt<<<(COUT * CIN) / 256, 256, 0, stream>>>(flt, filtG);
    conv_mfma<<<2 * 7 * BB, 512, 0, stream>>>(imgT, filtG, out);   // 448 blocks
}